// Round 8
// baseline (150.835 us; speedup 1.0000x reference)
//
#include <hip/hip_runtime.h>

#define N_NODES 10000
#define KMAX    128
#define PREP_TOT (640000 + 16384 + 65536 + 131072 + 32768)   // = 885760 = 3460*256

typedef __attribute__((ext_vector_type(8))) short short8v;
typedef __attribute__((ext_vector_type(4))) float f32x4;

// ---- bf16 helpers ----------------------------------------------------------
__device__ inline unsigned short f2bf(float f) {
    unsigned int u = __float_as_uint(f);
    return (unsigned short)((u + 0x7fffu + ((u >> 16) & 1u)) >> 16);
}
__device__ inline float bflo(unsigned int u) { return __uint_as_float(u << 16); }
__device__ inline float bfhi(unsigned int u) { return __uint_as_float(u & 0xffff0000u); }

struct Prm {
    const float *x, *rzw, *w1, *rw1, *w2, *rw2, *w3, *rw3;
    unsigned short *cat1b, *rzwT, *w1T, *w2T, *w3T;
};

// ---------------------------------------------------------------------------
// Fused prep + symmetric half-scan (unchanged from R7).
// ---------------------------------------------------------------------------
__global__ __launch_bounds__(256) void prep_scan(
    Prm p, const float* __restrict__ adj, int* __restrict__ ell, int* __restrict__ cnt)
{
    int gi = blockIdx.x * 256 + threadIdx.x;
    if (gi < PREP_TOT) {
        int i = gi;
        if (i < 640000) {
            float2 v = reinterpret_cast<const float2*>(p.x)[i];
            unsigned int pk = (unsigned int)f2bf(v.x) | ((unsigned int)f2bf(v.y) << 16);
            int row = i >> 6, c = (i & 63) * 2;
            *reinterpret_cast<unsigned int*>(p.cat1b + (size_t)row * 256 + 128 + c) = pk;
            goto scan;
        }
        i -= 640000;
        if (i < 16384) { int n = i >> 7, k = i & 127; p.rzwT[i] = f2bf(p.rzw[k * 128 + n]); goto scan; }
        i -= 16384;
        if (i < 65536) {
            int n = i >> 8, k = i & 255;
            p.w1T[i] = f2bf((k < 128) ? p.w1[k * 256 + n] : p.rw1[(k - 128) * 256 + n]);
            goto scan;
        }
        i -= 65536;
        if (i < 131072) {
            int n = i >> 9, k = i & 511;
            p.w2T[i] = f2bf((k < 256) ? p.w2[k * 256 + n] : p.rw2[(k - 256) * 256 + n]);
            goto scan;
        }
        i -= 131072;
        {
            int n = i >> 8, k = i & 255;
            float v = 0.0f;
            if (n < 40)      v = p.w3[k * 40 + n];
            else if (n < 80) v = p.rw3[k * 40 + (n - 40)];
            p.w3T[i] = f2bf(v);
        }
    }
scan:
    {
        int row = blockIdx.x;
        const float4* rp = reinterpret_cast<const float4*>(adj + (size_t)row * N_NODES);
        for (int f = (row >> 2) + threadIdx.x; f < N_NODES / 4; f += 256) {
            float4 v = rp[f];
            int base = f * 4;
            #pragma unroll
            for (int s = 0; s < 4; ++s) {
                float e = (s == 0) ? v.x : (s == 1) ? v.y : (s == 2) ? v.z : v.w;
                int j = base + s;
                if (e != 0.0f && j >= row) {
                    int q = atomicAdd(&cnt[row], 1);
                    if (q < KMAX) ell[(size_t)row * KMAX + q] = j;
                    if (j > row) {
                        int q2 = atomicAdd(&cnt[j], 1);
                        if (q2 < KMAX) ell[(size_t)j * KMAX + q2] = row;
                    }
                }
            }
        }
    }
}

// ---------------------------------------------------------------------------
// Sparse aggregation, occupancy-optimized: 256-thread blocks, TPR threads per
// row (row count per block = 256/TPR), 4 channels/thread via uint2 gathers.
// Edge-list / cnt loads are row-group-uniform (broadcast, L2-hot). f32
// accumulate in e-ascending order (bit-identical to previous rounds).
// gate != null: early-out when gate[0] == 0 (rezero branch, alpha==0).
// ---------------------------------------------------------------------------
template<int TPR>
__global__ __launch_bounds__(256) void agg_v(
    const unsigned short* __restrict__ hb, int hstride,
    const int* __restrict__ ell, const int* __restrict__ cnt,
    unsigned short* __restrict__ outB, int ostride, int mean_flag,
    const float* __restrict__ gate)
{
    if (gate && gate[0] == 0.0f) return;
    const int rpb = 256 / TPR;
    const int sub = threadIdx.x / TPR;
    const int ln  = threadIdx.x % TPR;
    const int row = blockIdx.x * rpb + sub;
    if (row >= N_NODES) return;

    int len = cnt[row]; if (len > KMAX) len = KMAX; if (len < 1) len = 1;
    const int* el = ell + (size_t)row * KMAX;

    float a0 = 0.0f, a1 = 0.0f, a2 = 0.0f, a3 = 0.0f;
    #pragma unroll 4
    for (int e = 0; e < len; ++e) {
        int j = el[e];
        int d = cnt[j]; if (d > KMAX) d = KMAX; if (d < 1) d = 1;
        float w = rsqrtf((float)d);
        uint2 u = *reinterpret_cast<const uint2*>(hb + (size_t)j * hstride + 4 * ln);
        a0 += w * bflo(u.x);
        a1 += w * bfhi(u.x);
        a2 += w * bflo(u.y);
        a3 += w * bfhi(u.y);
    }
    float fd = (float)len;
    float s = mean_flag ? rsqrtf(fd) / fd : rsqrtf(fd);
    uint2 o;
    o.x = (unsigned int)f2bf(a0 * s) | ((unsigned int)f2bf(a1 * s) << 16);
    o.y = (unsigned int)f2bf(a2 * s) | ((unsigned int)f2bf(a3 * s) << 16);
    *reinterpret_cast<uint2*>(outB + (size_t)row * ostride + 4 * ln) = o;
}

// ---------------------------------------------------------------------------
// Final L3 aggregation: out[row,0:40] += deg^-1.5 * sum_j dis_j * Pb[j,:]
// 32 thr/row (10 active, 4ch each), 8 rows/block.
// ---------------------------------------------------------------------------
__global__ __launch_bounds__(256) void agg_add40(
    const unsigned short* __restrict__ Pb,
    const int* __restrict__ ell, const int* __restrict__ cnt,
    float* __restrict__ out)
{
    const int sub = threadIdx.x >> 5;
    const int ln  = threadIdx.x & 31;
    const int row = blockIdx.x * 8 + sub;
    if (row >= N_NODES || ln >= 10) return;

    int len = cnt[row]; if (len > KMAX) len = KMAX; if (len < 1) len = 1;
    const int* el = ell + (size_t)row * KMAX;

    float a0 = 0.0f, a1 = 0.0f, a2 = 0.0f, a3 = 0.0f;
    #pragma unroll 4
    for (int e = 0; e < len; ++e) {
        int j = el[e];
        int d = cnt[j]; if (d > KMAX) d = KMAX; if (d < 1) d = 1;
        float w = rsqrtf((float)d);
        uint2 u = *reinterpret_cast<const uint2*>(Pb + (size_t)j * 40 + 4 * ln);
        a0 += w * bflo(u.x);
        a1 += w * bfhi(u.x);
        a2 += w * bflo(u.y);
        a3 += w * bfhi(u.y);
    }
    float fd = (float)len;
    float s = rsqrtf(fd) / fd;
    float4* op = reinterpret_cast<float4*>(out + (size_t)row * 40 + 4 * ln);
    float4 v = *op;
    v.x += a0 * s; v.y += a1 * s; v.z += a2 * s; v.w += a3 * s;
    *op = v;
}

// ---------------------------------------------------------------------------
// bf16 MFMA GEMM, M-tile templated: C = A[M x K] @ BT[CoPad][K]^T.
// MT x 64 block tile, 4 waves each (MT/4) x 64 rows, BK=32.
// modes: 0 = (+bias)(+relu) bf16 out; 1 = rezero (addend + alpha*acc) bf16,
//        early-out when alpha==0; 2 = col<40 -> Pb bf16, 40<=col<80 -> outQ f32.
// ---------------------------------------------------------------------------
template<int MT>
__global__ __launch_bounds__(256) void gemm_mfma(
    const unsigned short* __restrict__ A, int M, int lda, int K,
    const unsigned short* __restrict__ BT,
    int Co, const float* __restrict__ bias, int relu_flag, int mode,
    const float* __restrict__ alpha_ptr, const float* __restrict__ addend,
    unsigned short* __restrict__ outB, int ostride, int ooff,
    unsigned short* __restrict__ Pb, float* __restrict__ outQ)
{
    if (mode == 1 && alpha_ptr[0] == 0.0f) return;  // h-half already holds x
    constexpr int WM = MT / 64;              // 16-row MFMA tiles per wave (2 or 1)
    __shared__ unsigned short As[MT][40];    // +8 pad: 2-way bank alias (free)
    __shared__ unsigned short Bs[64][40];
    const int tid  = threadIdx.x;
    const int lane = tid & 63;
    const int wid  = tid >> 6;               // wave -> rows [wid*(MT/4), ...)
    const int fr   = lane & 15, fg = lane >> 4;
    const int bm   = blockIdx.x * MT;
    const int bn   = blockIdx.y * 64;

    f32x4 acc[WM][4] = {};

    for (int k0 = 0; k0 < K; k0 += 32) {
        #pragma unroll
        for (int pp = 0; pp < MT / 64; ++pp) {
            int i = tid + pp * 256;
            int r = i >> 2, kc = (i & 3) * 8;
            int arow = bm + r;
            uint4 v = make_uint4(0u, 0u, 0u, 0u);
            if (arow < M)
                v = *reinterpret_cast<const uint4*>(A + (size_t)arow * lda + k0 + kc);
            *reinterpret_cast<uint4*>(&As[r][kc]) = v;
        }
        {
            int c = tid >> 2, kc = (tid & 3) * 8;
            uint4 v = *reinterpret_cast<const uint4*>(BT + (size_t)(bn + c) * K + k0 + kc);
            *reinterpret_cast<uint4*>(&Bs[c][kc]) = v;
        }
        __syncthreads();

        short8v af[WM], bf[4];
        #pragma unroll
        for (int m = 0; m < WM; ++m)
            af[m] = *reinterpret_cast<const short8v*>(&As[wid * (MT / 4) + m * 16 + fr][fg * 8]);
        #pragma unroll
        for (int n = 0; n < 4; ++n)
            bf[n] = *reinterpret_cast<const short8v*>(&Bs[n * 16 + fr][fg * 8]);
        #pragma unroll
        for (int m = 0; m < WM; ++m)
            #pragma unroll
            for (int n = 0; n < 4; ++n)
                acc[m][n] = __builtin_amdgcn_mfma_f32_16x16x32_bf16(af[m], bf[n], acc[m][n], 0, 0, 0);
        __syncthreads();
    }

    // C/D layout: col = lane&15, row = 4*(lane>>4)+reg  [HW-verified]
    #pragma unroll
    for (int m = 0; m < WM; ++m) {
        #pragma unroll
        for (int n = 0; n < 4; ++n) {
            int col = bn + n * 16 + fr;
            if (col >= Co) continue;
            #pragma unroll
            for (int r = 0; r < 4; ++r) {
                int row = bm + wid * (MT / 4) + m * 16 + fg * 4 + r;
                if (row >= M) continue;
                float v = acc[m][n][r];
                if (mode == 0) {
                    if (bias) v += bias[col];
                    if (relu_flag) v = fmaxf(v, 0.0f);
                    outB[(size_t)row * ostride + ooff + col] = f2bf(v);
                } else if (mode == 1) {
                    v = addend[(size_t)row * 128 + col] + alpha_ptr[0] * v;
                    outB[(size_t)row * ostride + ooff + col] = f2bf(v);
                } else {
                    if (col < 40)      Pb[(size_t)row * 40 + col] = f2bf(v);
                    else if (col < 80) outQ[(size_t)row * 40 + (col - 40)] = v + bias[col - 40];
                }
            }
        }
    }
}

extern "C" void kernel_launch(void* const* d_in, const int* in_sizes, int n_in,
                              void* d_out, int out_size, void* d_ws, size_t ws_size,
                              hipStream_t stream)
{
    (void)in_sizes; (void)n_in; (void)out_size; (void)ws_size;
    const float* x     = (const float*)d_in[0];
    const float* adj   = (const float*)d_in[1];
    const float* alpha = (const float*)d_in[2];
    const float* b1    = (const float*)d_in[6];
    const float* b2    = (const float*)d_in[9];
    const float* b3    = (const float*)d_in[12];
    float* out = (float*)d_out;

    char* ws = (char*)d_ws;
    size_t off = 0;
    auto alloc = [&](size_t bytes) -> char* {
        char* q = ws + off;
        off = (off + bytes + 255) & ~(size_t)255;
        return q;
    };
    int*            cnt    = (int*)  alloc((size_t)N_NODES * 4);
    int*            ell    = (int*)  alloc((size_t)N_NODES * KMAX * 4);
    unsigned short* aggxb  = (unsigned short*)alloc((size_t)N_NODES * 128 * 2);
    unsigned short* cat1b  = (unsigned short*)alloc((size_t)N_NODES * 256 * 2); // [agg|h0]
    unsigned short* cat2b  = (unsigned short*)alloc((size_t)N_NODES * 512 * 2); // [agg|h1]
    unsigned short* h2b    = (unsigned short*)alloc((size_t)N_NODES * 256 * 2);
    unsigned short* Pb     = (unsigned short*)alloc((size_t)N_NODES * 40 * 2);
    unsigned short* rzwT   = (unsigned short*)alloc((size_t)128 * 128 * 2);
    unsigned short* w1T    = (unsigned short*)alloc((size_t)256 * 256 * 2);
    unsigned short* w2T    = (unsigned short*)alloc((size_t)256 * 512 * 2);
    unsigned short* w3T    = (unsigned short*)alloc((size_t)128 * 256 * 2);

    Prm p;
    p.x = x; p.rzw = (const float*)d_in[3];
    p.w1 = (const float*)d_in[4]; p.rw1 = (const float*)d_in[5];
    p.w2 = (const float*)d_in[7]; p.rw2 = (const float*)d_in[8];
    p.w3 = (const float*)d_in[10]; p.rw3 = (const float*)d_in[11];
    p.cat1b = cat1b; p.rzwT = rzwT; p.w1T = w1T; p.w2T = w2T; p.w3T = w3T;

    // zero edge counters, then fused prep + 200 MB half-scan
    hipMemsetAsync(cnt, 0, (size_t)N_NODES * 4, stream);
    prep_scan<<<N_NODES, 256, 0, stream>>>(p, adj, ell, cnt);

    // rezero branch (both gated on alpha==0; h0 = x already staged by prep)
    agg_v<32><<<1250, 256, 0, stream>>>(cat1b + 128, 256, ell, cnt, aggxb, 128, 0, alpha);
    gemm_mfma<128><<<dim3(79, 2), 256, 0, stream>>>(aggxb, N_NODES, 128, 128, rzwT,
                                                    128, nullptr, 0, 1, alpha, x,
                                                    cat1b, 256, 128, nullptr, nullptr);

    // layer 1: agg -> cat1[:,0:128]; h1 = relu(cat1@[w1;rw1]+b1) -> cat2[:,256:512]
    agg_v<32><<<1250, 256, 0, stream>>>(cat1b + 128, 256, ell, cnt, cat1b, 256, 1, nullptr);
    gemm_mfma<128><<<dim3(79, 4), 256, 0, stream>>>(cat1b, N_NODES, 256, 256, w1T,
                                                    256, b1, 1, 0, nullptr, nullptr,
                                                    cat2b, 512, 256, nullptr, nullptr);

    // layer 2: agg -> cat2[:,0:256]; h2 = relu(cat2@[w2;rw2]+b2) -> h2b
    agg_v<64><<<2500, 256, 0, stream>>>(cat2b + 256, 512, ell, cnt, cat2b, 512, 1, nullptr);
    gemm_mfma<128><<<dim3(79, 4), 256, 0, stream>>>(cat2b, N_NODES, 512, 512, w2T,
                                                    256, b2, 1, 0, nullptr, nullptr,
                                                    h2b, 256, 0, nullptr, nullptr);

    // layer 3 (reordered): P = h2@w3 -> Pb, out = h2@rw3 + b3; out += Dm·Â·P
    gemm_mfma<64><<<dim3(157, 2), 256, 0, stream>>>(h2b, N_NODES, 256, 256, w3T,
                                                    80, b3, 0, 2, nullptr, nullptr,
                                                    nullptr, 0, 0, Pb, out);
    agg_add40<<<1250, 256, 0, stream>>>(Pb, ell, cnt, out);
}

// Round 9
// 147.475 us; speedup vs baseline: 1.0228x; 1.0228x over previous
//
#include <hip/hip_runtime.h>

#define N_NODES 10000
#define KMAX    128
#define PREP_TOT (640000 + 16384 + 65536 + 131072 + 32768)   // = 885760

typedef __attribute__((ext_vector_type(8))) short short8v;
typedef __attribute__((ext_vector_type(4))) float f32x4;

__device__ inline unsigned short f2bf(float f) {
    unsigned int u = __float_as_uint(f);
    return (unsigned short)((u + 0x7fffu + ((u >> 16) & 1u)) >> 16);
}
__device__ inline float bflo(unsigned int u) { return __uint_as_float(u << 16); }
__device__ inline float bfhi(unsigned int u) { return __uint_as_float(u & 0xffff0000u); }

struct Prm {
    const float *x, *rzw, *w1, *rw1, *w2, *rw2, *w3, *rw3;
    unsigned short *xb, *rzwT, *w1T, *w2T, *w3T;
};

// ---------------------------------------------------------------------------
// Fused prep + symmetric half-scan (x -> xb bf16; weights -> bf16 [n][k]).
// ---------------------------------------------------------------------------
__global__ __launch_bounds__(256) void prep_scan(
    Prm p, const float* __restrict__ adj, int* __restrict__ ell, int* __restrict__ cnt)
{
    int gi = blockIdx.x * 256 + threadIdx.x;
    if (gi < PREP_TOT) {
        int i = gi;
        if (i < 640000) {
            float2 v = reinterpret_cast<const float2*>(p.x)[i];
            unsigned int pk = (unsigned int)f2bf(v.x) | ((unsigned int)f2bf(v.y) << 16);
            int row = i >> 6, c = (i & 63) * 2;
            *reinterpret_cast<unsigned int*>(p.xb + (size_t)row * 128 + c) = pk;
            goto scan;
        }
        i -= 640000;
        if (i < 16384) { int n = i >> 7, k = i & 127; p.rzwT[i] = f2bf(p.rzw[k * 128 + n]); goto scan; }
        i -= 16384;
        if (i < 65536) {
            int n = i >> 8, k = i & 255;
            p.w1T[i] = f2bf((k < 128) ? p.w1[k * 256 + n] : p.rw1[(k - 128) * 256 + n]);
            goto scan;
        }
        i -= 65536;
        if (i < 131072) {
            int n = i >> 9, k = i & 511;
            p.w2T[i] = f2bf((k < 256) ? p.w2[k * 256 + n] : p.rw2[(k - 256) * 256 + n]);
            goto scan;
        }
        i -= 131072;
        {
            int n = i >> 8, k = i & 255;
            float v = 0.0f;
            if (n < 40)      v = p.w3[k * 40 + n];
            else if (n < 80) v = p.rw3[k * 40 + (n - 40)];
            p.w3T[i] = f2bf(v);
        }
    }
scan:
    {
        int row = blockIdx.x;
        const float4* rp = reinterpret_cast<const float4*>(adj + (size_t)row * N_NODES);
        for (int f = (row >> 2) + threadIdx.x; f < N_NODES / 4; f += 256) {
            float4 v = rp[f];
            int base = f * 4;
            #pragma unroll
            for (int s = 0; s < 4; ++s) {
                float e = (s == 0) ? v.x : (s == 1) ? v.y : (s == 2) ? v.z : v.w;
                int j = base + s;
                if (e != 0.0f && j >= row) {
                    int q = atomicAdd(&cnt[row], 1);
                    if (q < KMAX) ell[(size_t)row * KMAX + q] = j;
                    if (j > row) {
                        int q2 = atomicAdd(&cnt[j], 1);
                        if (q2 < KMAX) ell[(size_t)j * KMAX + q2] = row;
                    }
                }
            }
        }
    }
}

// ---------------------------------------------------------------------------
// Fused layer: 32-row slab per block. Phase A gather-agg + h-copy -> LDS;
// Phase B 32x256 MFMA GEMM K=2*CIN, B-frags direct from L2-hot BT.
// src = alpha-selected gather/h source (device-uniform pick).
// ---------------------------------------------------------------------------
template<int CIN>
__global__ __launch_bounds__(256) void layer_fused(
    const unsigned short* __restrict__ src0,   // alpha==0 source
    const unsigned short* __restrict__ src1,   // alpha!=0 source (h0b)
    const float* __restrict__ alpha,           // null => always src0
    const int* __restrict__ ell, const int* __restrict__ cnt,
    const unsigned short* __restrict__ BT,
    const float* __restrict__ bias,
    unsigned short* __restrict__ outB)
{
    const unsigned short* hb = (alpha && alpha[0] != 0.0f) ? src1 : src0;
    constexpr int K   = 2 * CIN;
    constexpr int LDA = K + 8;
    constexpr int CPL = CIN / 8;
    __shared__ unsigned short As[32][LDA];
    const int r0 = blockIdx.x * 32;

    {
        const int sub = threadIdx.x >> 3;
        const int ln  = threadIdx.x & 7;
        const int row = r0 + sub;
        if (row < N_NODES) {
            int len = cnt[row]; if (len > KMAX) len = KMAX; if (len < 1) len = 1;
            const int* el = ell + (size_t)row * KMAX;
            float acc[CPL] = {};
            #pragma unroll 2
            for (int e = 0; e < len; ++e) {
                int j = el[e];
                int d = cnt[j]; if (d > KMAX) d = KMAX; if (d < 1) d = 1;
                float w = rsqrtf((float)d);
                const uint4* srcp = reinterpret_cast<const uint4*>(
                    hb + (size_t)j * CIN + ln * CPL);
                #pragma unroll
                for (int c4 = 0; c4 < CPL / 8; ++c4) {
                    uint4 u = srcp[c4];
                    acc[c4*8+0] += w * bflo(u.x); acc[c4*8+1] += w * bfhi(u.x);
                    acc[c4*8+2] += w * bflo(u.y); acc[c4*8+3] += w * bfhi(u.y);
                    acc[c4*8+4] += w * bflo(u.z); acc[c4*8+5] += w * bfhi(u.z);
                    acc[c4*8+6] += w * bflo(u.w); acc[c4*8+7] += w * bfhi(u.w);
                }
            }
            float fd = (float)len;
            float s  = rsqrtf(fd) / fd;
            #pragma unroll
            for (int c4 = 0; c4 < CPL / 8; ++c4) {
                uint4 pk;
                pk.x = (unsigned int)f2bf(acc[c4*8+0]*s) | ((unsigned int)f2bf(acc[c4*8+1]*s) << 16);
                pk.y = (unsigned int)f2bf(acc[c4*8+2]*s) | ((unsigned int)f2bf(acc[c4*8+3]*s) << 16);
                pk.z = (unsigned int)f2bf(acc[c4*8+4]*s) | ((unsigned int)f2bf(acc[c4*8+5]*s) << 16);
                pk.w = (unsigned int)f2bf(acc[c4*8+6]*s) | ((unsigned int)f2bf(acc[c4*8+7]*s) << 16);
                *reinterpret_cast<uint4*>(&As[sub][ln * CPL + c4 * 8]) = pk;
            }
            const uint4* hs = reinterpret_cast<const uint4*>(hb + (size_t)row * CIN + ln * CPL);
            #pragma unroll
            for (int c4 = 0; c4 < CPL / 8; ++c4)
                *reinterpret_cast<uint4*>(&As[sub][CIN + ln * CPL + c4 * 8]) = hs[c4];
        } else {
            uint4 z = make_uint4(0u, 0u, 0u, 0u);
            #pragma unroll
            for (int c4 = 0; c4 < CPL / 8; ++c4) {
                *reinterpret_cast<uint4*>(&As[sub][ln * CPL + c4 * 8]) = z;
                *reinterpret_cast<uint4*>(&As[sub][CIN + ln * CPL + c4 * 8]) = z;
            }
        }
    }
    __syncthreads();

    const int lane = threadIdx.x & 63;
    const int wid  = threadIdx.x >> 6;
    const int fr   = lane & 15, fg = lane >> 4;
    const int bn   = wid * 64;

    f32x4 acc[2][4] = {};
    for (int k0 = 0; k0 < K; k0 += 32) {
        short8v af[2], bf[4];
        #pragma unroll
        for (int m = 0; m < 2; ++m)
            af[m] = *reinterpret_cast<const short8v*>(&As[m * 16 + fr][k0 + fg * 8]);
        #pragma unroll
        for (int n = 0; n < 4; ++n)
            bf[n] = *reinterpret_cast<const short8v*>(
                BT + (size_t)(bn + n * 16 + fr) * K + k0 + fg * 8);
        #pragma unroll
        for (int m = 0; m < 2; ++m)
            #pragma unroll
            for (int n = 0; n < 4; ++n)
                acc[m][n] = __builtin_amdgcn_mfma_f32_16x16x32_bf16(af[m], bf[n], acc[m][n], 0, 0, 0);
    }

    #pragma unroll
    for (int m = 0; m < 2; ++m) {
        #pragma unroll
        for (int n = 0; n < 4; ++n) {
            int col = bn + n * 16 + fr;
            #pragma unroll
            for (int r = 0; r < 4; ++r) {
                int row = r0 + m * 16 + fg * 4 + r;
                if (row < N_NODES) {
                    float v = fmaxf(acc[m][n][r] + bias[col], 0.0f);
                    outB[(size_t)row * 256 + col] = f2bf(v);
                }
            }
        }
    }
}

// ---------------------------------------------------------------------------
// Fused rezero (gated no-op when alpha==0): agg(x)@rzwT, h0 = x + a*acc.
// ---------------------------------------------------------------------------
__global__ __launch_bounds__(256) void rz_fused(
    const unsigned short* __restrict__ xb, const float* __restrict__ x,
    const int* __restrict__ ell, const int* __restrict__ cnt,
    const unsigned short* __restrict__ rzwT,
    const float* __restrict__ alpha,
    unsigned short* __restrict__ h0b)
{
    float av = alpha[0];
    if (av == 0.0f) return;
    __shared__ unsigned short As[32][136];
    const int r0 = blockIdx.x * 32;
    {
        const int sub = threadIdx.x >> 3;
        const int ln  = threadIdx.x & 7;
        const int row = r0 + sub;
        if (row < N_NODES) {
            int len = cnt[row]; if (len > KMAX) len = KMAX; if (len < 1) len = 1;
            const int* el = ell + (size_t)row * KMAX;
            float acc[16] = {};
            #pragma unroll 2
            for (int e = 0; e < len; ++e) {
                int j = el[e];
                int d = cnt[j]; if (d > KMAX) d = KMAX; if (d < 1) d = 1;
                float w = rsqrtf((float)d);
                const uint4* srcp = reinterpret_cast<const uint4*>(xb + (size_t)j * 128 + ln * 16);
                #pragma unroll
                for (int c4 = 0; c4 < 2; ++c4) {
                    uint4 u = srcp[c4];
                    acc[c4*8+0] += w * bflo(u.x); acc[c4*8+1] += w * bfhi(u.x);
                    acc[c4*8+2] += w * bflo(u.y); acc[c4*8+3] += w * bfhi(u.y);
                    acc[c4*8+4] += w * bflo(u.z); acc[c4*8+5] += w * bfhi(u.z);
                    acc[c4*8+6] += w * bflo(u.w); acc[c4*8+7] += w * bfhi(u.w);
                }
            }
            float s = rsqrtf((float)len);
            #pragma unroll
            for (int c4 = 0; c4 < 2; ++c4) {
                uint4 pk;
                pk.x = (unsigned int)f2bf(acc[c4*8+0]*s) | ((unsigned int)f2bf(acc[c4*8+1]*s) << 16);
                pk.y = (unsigned int)f2bf(acc[c4*8+2]*s) | ((unsigned int)f2bf(acc[c4*8+3]*s) << 16);
                pk.z = (unsigned int)f2bf(acc[c4*8+4]*s) | ((unsigned int)f2bf(acc[c4*8+5]*s) << 16);
                pk.w = (unsigned int)f2bf(acc[c4*8+6]*s) | ((unsigned int)f2bf(acc[c4*8+7]*s) << 16);
                *reinterpret_cast<uint4*>(&As[sub][ln * 16 + c4 * 8]) = pk;
            }
        } else {
            uint4 z = make_uint4(0u, 0u, 0u, 0u);
            *reinterpret_cast<uint4*>(&As[sub][ln * 16]) = z;
            *reinterpret_cast<uint4*>(&As[sub][ln * 16 + 8]) = z;
        }
    }
    __syncthreads();

    const int lane = threadIdx.x & 63;
    const int wid  = threadIdx.x >> 6;
    const int wr   = wid >> 1, wc = wid & 1;
    const int fr   = lane & 15, fg = lane >> 4;

    f32x4 acc[4] = {};
    for (int k0 = 0; k0 < 128; k0 += 32) {
        short8v af = *reinterpret_cast<const short8v*>(&As[wr * 16 + fr][k0 + fg * 8]);
        #pragma unroll
        for (int n = 0; n < 4; ++n) {
            short8v bf = *reinterpret_cast<const short8v*>(
                rzwT + (size_t)(wc * 64 + n * 16 + fr) * 128 + k0 + fg * 8);
            acc[n] = __builtin_amdgcn_mfma_f32_16x16x32_bf16(af, bf, acc[n], 0, 0, 0);
        }
    }
    #pragma unroll
    for (int n = 0; n < 4; ++n) {
        int col = wc * 64 + n * 16 + fr;
        #pragma unroll
        for (int r = 0; r < 4; ++r) {
            int row = r0 + wr * 16 + fg * 4 + r;
            if (row < N_NODES) {
                float v = x[(size_t)row * 128 + col] + av * acc[n][r];
                h0b[(size_t)row * 128 + col] = f2bf(v);
            }
        }
    }
}

// ---------------------------------------------------------------------------
// Layer-3 GEMM (reordered): col<40 -> Pb bf16 (h2@w3); 40<=col<80 ->
// out f32 = h2@rw3 + b3.
// ---------------------------------------------------------------------------
__global__ __launch_bounds__(256) void gemm3(
    const unsigned short* __restrict__ A, const unsigned short* __restrict__ BT,
    const float* __restrict__ bias,
    unsigned short* __restrict__ Pb, float* __restrict__ outQ)
{
    constexpr int K = 256;
    __shared__ unsigned short As[64][40];
    __shared__ unsigned short Bs[64][40];
    const int tid  = threadIdx.x;
    const int lane = tid & 63;
    const int wid  = tid >> 6;
    const int fr   = lane & 15, fg = lane >> 4;
    const int bm   = blockIdx.x * 64;
    const int bn   = blockIdx.y * 64;

    f32x4 acc[4] = {};
    for (int k0 = 0; k0 < K; k0 += 32) {
        {
            int r = tid >> 2, kc = (tid & 3) * 8;
            int arow = bm + r;
            uint4 v = make_uint4(0u, 0u, 0u, 0u);
            if (arow < N_NODES)
                v = *reinterpret_cast<const uint4*>(A + (size_t)arow * K + k0 + kc);
            *reinterpret_cast<uint4*>(&As[r][kc]) = v;
            uint4 b = *reinterpret_cast<const uint4*>(BT + (size_t)(bn + r) * K + k0 + kc);
            *reinterpret_cast<uint4*>(&Bs[r][kc]) = b;
        }
        __syncthreads();
        short8v af = *reinterpret_cast<const short8v*>(&As[wid * 16 + fr][fg * 8]);
        #pragma unroll
        for (int n = 0; n < 4; ++n) {
            short8v bf = *reinterpret_cast<const short8v*>(&Bs[n * 16 + fr][fg * 8]);
            acc[n] = __builtin_amdgcn_mfma_f32_16x16x32_bf16(af, bf, acc[n], 0, 0, 0);
        }
        __syncthreads();
    }
    #pragma unroll
    for (int n = 0; n < 4; ++n) {
        int col = bn + n * 16 + fr;
        #pragma unroll
        for (int r = 0; r < 4; ++r) {
            int row = bm + wid * 16 + fg * 4 + r;
            if (row >= N_NODES) continue;
            float v = acc[n][r];
            if (col < 40)      Pb[(size_t)row * 40 + col] = f2bf(v);
            else if (col < 80) outQ[(size_t)row * 40 + (col - 40)] = v + bias[col - 40];
        }
    }
}

// ---------------------------------------------------------------------------
// Final L3 aggregation: out[row,0:40] += deg^-1.5 * sum_j dis_j * Pb[j,:]
// ---------------------------------------------------------------------------
__global__ __launch_bounds__(256) void agg_add40(
    const unsigned short* __restrict__ Pb,
    const int* __restrict__ ell, const int* __restrict__ cnt,
    float* __restrict__ out)
{
    const int sub = threadIdx.x >> 5;
    const int ln  = threadIdx.x & 31;
    const int row = blockIdx.x * 8 + sub;
    if (row >= N_NODES || ln >= 10) return;

    int len = cnt[row]; if (len > KMAX) len = KMAX; if (len < 1) len = 1;
    const int* el = ell + (size_t)row * KMAX;

    float a0 = 0.0f, a1 = 0.0f, a2 = 0.0f, a3 = 0.0f;
    #pragma unroll 4
    for (int e = 0; e < len; ++e) {
        int j = el[e];
        int d = cnt[j]; if (d > KMAX) d = KMAX; if (d < 1) d = 1;
        float w = rsqrtf((float)d);
        uint2 u = *reinterpret_cast<const uint2*>(Pb + (size_t)j * 40 + 4 * ln);
        a0 += w * bflo(u.x);
        a1 += w * bfhi(u.x);
        a2 += w * bflo(u.y);
        a3 += w * bfhi(u.y);
    }
    float fd = (float)len;
    float s = rsqrtf(fd) / fd;
    float4* op = reinterpret_cast<float4*>(out + (size_t)row * 40 + 4 * ln);
    float4 v = *op;
    v.x += a0 * s; v.y += a1 * s; v.z += a2 * s; v.w += a3 * s;
    *op = v;
}

extern "C" void kernel_launch(void* const* d_in, const int* in_sizes, int n_in,
                              void* d_out, int out_size, void* d_ws, size_t ws_size,
                              hipStream_t stream)
{
    (void)in_sizes; (void)n_in; (void)out_size; (void)ws_size;
    const float* x     = (const float*)d_in[0];
    const float* adj   = (const float*)d_in[1];
    const float* alpha = (const float*)d_in[2];
    const float* b1    = (const float*)d_in[6];
    const float* b2    = (const float*)d_in[9];
    const float* b3    = (const float*)d_in[12];
    float* out = (float*)d_out;

    char* ws = (char*)d_ws;
    size_t off = 0;
    auto alloc = [&](size_t bytes) -> char* {
        char* q = ws + off;
        off = (off + bytes + 255) & ~(size_t)255;
        return q;
    };
    int*            cnt  = (int*)  alloc((size_t)N_NODES * 4);
    int*            ell  = (int*)  alloc((size_t)N_NODES * KMAX * 4);
    unsigned short* xb   = (unsigned short*)alloc((size_t)N_NODES * 128 * 2);
    unsigned short* h0b  = (unsigned short*)alloc((size_t)N_NODES * 128 * 2);
    unsigned short* h1b  = (unsigned short*)alloc((size_t)N_NODES * 256 * 2);
    unsigned short* h2b  = (unsigned short*)alloc((size_t)N_NODES * 256 * 2);
    unsigned short* Pb   = (unsigned short*)alloc((size_t)N_NODES * 40 * 2);
    unsigned short* rzwT = (unsigned short*)alloc((size_t)128 * 128 * 2);
    unsigned short* w1T  = (unsigned short*)alloc((size_t)256 * 256 * 2);
    unsigned short* w2T  = (unsigned short*)alloc((size_t)256 * 512 * 2);
    unsigned short* w3T  = (unsigned short*)alloc((size_t)128 * 256 * 2);

    Prm p;
    p.x = x; p.rzw = (const float*)d_in[3];
    p.w1 = (const float*)d_in[4]; p.rw1 = (const float*)d_in[5];
    p.w2 = (const float*)d_in[7]; p.rw2 = (const float*)d_in[8];
    p.w3 = (const float*)d_in[10]; p.rw3 = (const float*)d_in[11];
    p.xb = xb; p.rzwT = rzwT; p.w1T = w1T; p.w2T = w2T; p.w3T = w3T;

    const int NSLAB = (N_NODES + 31) / 32;   // 313

    hipMemsetAsync(cnt, 0, (size_t)N_NODES * 4, stream);
    prep_scan<<<N_NODES, 256, 0, stream>>>(p, adj, ell, cnt);
    rz_fused<<<NSLAB, 256, 0, stream>>>(xb, x, ell, cnt, rzwT, alpha, h0b);
    layer_fused<128><<<NSLAB, 256, 0, stream>>>(xb, h0b, alpha, ell, cnt, w1T, b1, h1b);
    layer_fused<256><<<NSLAB, 256, 0, stream>>>(h1b, h1b, nullptr, ell, cnt, w2T, b2, h2b);
    gemm3<<<dim3((N_NODES + 63) / 64, 2), 256, 0, stream>>>(h2b, w3T, b3, Pb, out);
    agg_add40<<<1250, 256, 0, stream>>>(Pb, ell, cnt, out);
}

// Round 10
// 140.418 us; speedup vs baseline: 1.0742x; 1.0503x over previous
//
#include <hip/hip_runtime.h>

#define N_NODES 10000
#define KMAX    128
#define PREP_TOT (640000 + 16384 + 65536 + 131072 + 32768)   // = 885760

typedef __attribute__((ext_vector_type(8))) short short8v;
typedef __attribute__((ext_vector_type(4))) float f32x4;

__device__ inline unsigned short f2bf(float f) {
    unsigned int u = __float_as_uint(f);
    return (unsigned short)((u + 0x7fffu + ((u >> 16) & 1u)) >> 16);
}
__device__ inline float bflo(unsigned int u) { return __uint_as_float(u << 16); }
__device__ inline float bfhi(unsigned int u) { return __uint_as_float(u & 0xffff0000u); }

struct Prm {
    const float *x, *rzw, *w1, *rw1, *w2, *rw2, *w3, *rw3;
    unsigned short *xb, *rzwT, *w1T, *w2T, *w3T;
};

__global__ __launch_bounds__(256) void zero_cnt(int* __restrict__ cnt)
{
    int i = blockIdx.x * 256 + threadIdx.x;
    if (i < N_NODES) cnt[i] = 0;
}

// ---------------------------------------------------------------------------
// Prep work distributor (x -> xb bf16; weights -> bf16 [n][k] concat/merge).
// ---------------------------------------------------------------------------
__device__ inline void do_prep(int i, const Prm& p)
{
    if (i < 640000) {
        float2 v = reinterpret_cast<const float2*>(p.x)[i];
        unsigned int pk = (unsigned int)f2bf(v.x) | ((unsigned int)f2bf(v.y) << 16);
        int row = i >> 6, c = (i & 63) * 2;
        *reinterpret_cast<unsigned int*>(p.xb + (size_t)row * 128 + c) = pk;
        return;
    }
    i -= 640000;
    if (i < 16384) { int n = i >> 7, k = i & 127; p.rzwT[i] = f2bf(p.rzw[k * 128 + n]); return; }
    i -= 16384;
    if (i < 65536) {
        int n = i >> 8, k = i & 255;
        p.w1T[i] = f2bf((k < 128) ? p.w1[k * 256 + n] : p.rw1[(k - 128) * 256 + n]);
        return;
    }
    i -= 65536;
    if (i < 131072) {
        int n = i >> 9, k = i & 511;
        p.w2T[i] = f2bf((k < 256) ? p.w2[k * 256 + n] : p.rw2[(k - 256) * 256 + n]);
        return;
    }
    i -= 131072;
    {
        int n = i >> 8, k = i & 255;
        float v = 0.0f;
        if (n < 40)      v = p.w3[k * 40 + n];
        else if (n < 80) v = p.rw3[k * 40 + (n - 40)];
        p.w3T[i] = f2bf(v);
    }
}

// ---------------------------------------------------------------------------
// Fused prep + balanced symmetric half-scan: block b scans rows b and
// 9999-b (j >= row each) -> every block reads ~40 KB (perfect balance).
// ---------------------------------------------------------------------------
__global__ __launch_bounds__(256) void prep_scan(
    Prm p, const float* __restrict__ adj, int* __restrict__ ell, int* __restrict__ cnt)
{
    int gi = blockIdx.x * 256 + threadIdx.x;
    if (gi < PREP_TOT) do_prep(gi, p);

    const int rows[2] = { (int)blockIdx.x, N_NODES - 1 - (int)blockIdx.x };
    #pragma unroll
    for (int t = 0; t < 2; ++t) {
        int row = rows[t];
        const float4* rp = reinterpret_cast<const float4*>(adj + (size_t)row * N_NODES);
        for (int f = (row >> 2) + threadIdx.x; f < N_NODES / 4; f += 256) {
            float4 v = rp[f];
            int base = f * 4;
            #pragma unroll
            for (int s = 0; s < 4; ++s) {
                float e = (s == 0) ? v.x : (s == 1) ? v.y : (s == 2) ? v.z : v.w;
                int j = base + s;
                if (e != 0.0f && j >= row) {
                    int q = atomicAdd(&cnt[row], 1);
                    if (q < KMAX) ell[(size_t)row * KMAX + q] = j;
                    if (j > row) {
                        int q2 = atomicAdd(&cnt[j], 1);
                        if (q2 < KMAX) ell[(size_t)j * KMAX + q2] = row;
                    }
                }
            }
        }
    }
}

// ---------------------------------------------------------------------------
// Fused layer: 16-row slab per block (625 blocks). Phase A: LDS-staged edge
// lists (sj/sw), then gather-agg (16 lanes/row, CIN/16 ch/lane) + h-copy into
// LDS A-slab [agg | h]. Phase B: 16x256 MFMA GEMM, K=2*CIN, one 16-row m-tile,
// B-frags direct from L2-hot BT. bias+relu, bf16 out (stride 256).
// Per-channel accumulation order identical to R7/R9 -> bit-identical output.
// ---------------------------------------------------------------------------
template<int CIN>
__global__ __launch_bounds__(256) void layer_fused(
    const unsigned short* __restrict__ src0,   // alpha==0 gather/h source
    const unsigned short* __restrict__ src1,   // alpha!=0 source (h0b)
    const float* __restrict__ alpha,           // null => always src0
    const int* __restrict__ ell, const int* __restrict__ cnt,
    const unsigned short* __restrict__ BT,
    const float* __restrict__ bias,
    unsigned short* __restrict__ outB)
{
    const unsigned short* hb = (alpha && alpha[0] != 0.0f) ? src1 : src0;
    constexpr int K   = 2 * CIN;
    constexpr int LDA = K + 8;
    constexpr int CPL = CIN / 16;              // channels per lane (8 or 16)
    __shared__ unsigned short As[16][LDA];
    __shared__ int   sj[16][KMAX];
    __shared__ float sw[16][KMAX];
    const int r0  = blockIdx.x * 16;
    const int sub = threadIdx.x >> 4;          // slab row 0..15
    const int ln  = threadIdx.x & 15;          // 16 lanes per row
    const int row = r0 + sub;

    int len = 1;
    if (row < N_NODES) {
        len = cnt[row]; if (len > KMAX) len = KMAX; if (len < 1) len = 1;
        const int* el = ell + (size_t)row * KMAX;
        for (int e = ln; e < len; e += 16) {
            int j = el[e];
            int d = cnt[j]; if (d > KMAX) d = KMAX; if (d < 1) d = 1;
            sj[sub][e] = j;
            sw[sub][e] = rsqrtf((float)d);
        }
    }
    __syncthreads();

    if (row < N_NODES) {
        float acc[CPL] = {};
        #pragma unroll 2
        for (int e = 0; e < len; ++e) {
            int   j = sj[sub][e];
            float w = sw[sub][e];
            const uint4* srcp = reinterpret_cast<const uint4*>(hb + (size_t)j * CIN + ln * CPL);
            #pragma unroll
            for (int c4 = 0; c4 < CPL / 8; ++c4) {
                uint4 u = srcp[c4];
                acc[c4*8+0] += w * bflo(u.x); acc[c4*8+1] += w * bfhi(u.x);
                acc[c4*8+2] += w * bflo(u.y); acc[c4*8+3] += w * bfhi(u.y);
                acc[c4*8+4] += w * bflo(u.z); acc[c4*8+5] += w * bfhi(u.z);
                acc[c4*8+6] += w * bflo(u.w); acc[c4*8+7] += w * bfhi(u.w);
            }
        }
        float fd = (float)len;
        float s  = rsqrtf(fd) / fd;            // dis_i * invn_i (mean agg)
        #pragma unroll
        for (int c4 = 0; c4 < CPL / 8; ++c4) {
            uint4 pk;
            pk.x = (unsigned int)f2bf(acc[c4*8+0]*s) | ((unsigned int)f2bf(acc[c4*8+1]*s) << 16);
            pk.y = (unsigned int)f2bf(acc[c4*8+2]*s) | ((unsigned int)f2bf(acc[c4*8+3]*s) << 16);
            pk.z = (unsigned int)f2bf(acc[c4*8+4]*s) | ((unsigned int)f2bf(acc[c4*8+5]*s) << 16);
            pk.w = (unsigned int)f2bf(acc[c4*8+6]*s) | ((unsigned int)f2bf(acc[c4*8+7]*s) << 16);
            *reinterpret_cast<uint4*>(&As[sub][ln * CPL + c4 * 8]) = pk;
        }
        const uint4* hs = reinterpret_cast<const uint4*>(hb + (size_t)row * CIN + ln * CPL);
        #pragma unroll
        for (int c4 = 0; c4 < CPL / 8; ++c4)
            *reinterpret_cast<uint4*>(&As[sub][CIN + ln * CPL + c4 * 8]) = hs[c4];
    } else {
        uint4 z = make_uint4(0u, 0u, 0u, 0u);
        #pragma unroll
        for (int c4 = 0; c4 < CPL / 8; ++c4) {
            *reinterpret_cast<uint4*>(&As[sub][ln * CPL + c4 * 8]) = z;
            *reinterpret_cast<uint4*>(&As[sub][CIN + ln * CPL + c4 * 8]) = z;
        }
    }
    __syncthreads();

    // ---- Phase B: one 16-row m-tile x 256 cols ----------------------------
    const int lane = threadIdx.x & 63;
    const int wid  = threadIdx.x >> 6;         // wave -> cols [wid*64, +64)
    const int fr   = lane & 15, fg = lane >> 4;
    const int bn   = wid * 64;

    f32x4 acc4[4] = {};
    for (int k0 = 0; k0 < K; k0 += 32) {
        short8v af = *reinterpret_cast<const short8v*>(&As[fr][k0 + fg * 8]);
        #pragma unroll
        for (int n = 0; n < 4; ++n) {
            short8v bf = *reinterpret_cast<const short8v*>(
                BT + (size_t)(bn + n * 16 + fr) * K + k0 + fg * 8);
            acc4[n] = __builtin_amdgcn_mfma_f32_16x16x32_bf16(af, bf, acc4[n], 0, 0, 0);
        }
    }

    // C/D layout: col = lane&15, row = 4*(lane>>4)+reg  [HW-verified]
    #pragma unroll
    for (int n = 0; n < 4; ++n) {
        int col = bn + n * 16 + fr;
        #pragma unroll
        for (int r = 0; r < 4; ++r) {
            int orow = r0 + fg * 4 + r;
            if (orow < N_NODES) {
                float v = fmaxf(acc4[n][r] + bias[col], 0.0f);
                outB[(size_t)orow * 256 + col] = f2bf(v);
            }
        }
    }
}

// ---------------------------------------------------------------------------
// Fused rezero (gated no-op when alpha==0): agg(x)@rzwT, h0 = x + a*acc.
// ---------------------------------------------------------------------------
__global__ __launch_bounds__(256) void rz_fused(
    const unsigned short* __restrict__ xb, const float* __restrict__ x,
    const int* __restrict__ ell, const int* __restrict__ cnt,
    const unsigned short* __restrict__ rzwT,
    const float* __restrict__ alpha,
    unsigned short* __restrict__ h0b)
{
    float av = alpha[0];
    if (av == 0.0f) return;
    __shared__ unsigned short As[32][136];
    const int r0 = blockIdx.x * 32;
    {
        const int sub = threadIdx.x >> 3;
        const int ln  = threadIdx.x & 7;
        const int row = r0 + sub;
        if (row < N_NODES) {
            int len = cnt[row]; if (len > KMAX) len = KMAX; if (len < 1) len = 1;
            const int* el = ell + (size_t)row * KMAX;
            float acc[16] = {};
            #pragma unroll 2
            for (int e = 0; e < len; ++e) {
                int j = el[e];
                int d = cnt[j]; if (d > KMAX) d = KMAX; if (d < 1) d = 1;
                float w = rsqrtf((float)d);
                const uint4* srcp = reinterpret_cast<const uint4*>(xb + (size_t)j * 128 + ln * 16);
                #pragma unroll
                for (int c4 = 0; c4 < 2; ++c4) {
                    uint4 u = srcp[c4];
                    acc[c4*8+0] += w * bflo(u.x); acc[c4*8+1] += w * bfhi(u.x);
                    acc[c4*8+2] += w * bflo(u.y); acc[c4*8+3] += w * bfhi(u.y);
                    acc[c4*8+4] += w * bflo(u.z); acc[c4*8+5] += w * bfhi(u.z);
                    acc[c4*8+6] += w * bflo(u.w); acc[c4*8+7] += w * bfhi(u.w);
                }
            }
            float s = rsqrtf((float)len);
            #pragma unroll
            for (int c4 = 0; c4 < 2; ++c4) {
                uint4 pk;
                pk.x = (unsigned int)f2bf(acc[c4*8+0]*s) | ((unsigned int)f2bf(acc[c4*8+1]*s) << 16);
                pk.y = (unsigned int)f2bf(acc[c4*8+2]*s) | ((unsigned int)f2bf(acc[c4*8+3]*s) << 16);
                pk.z = (unsigned int)f2bf(acc[c4*8+4]*s) | ((unsigned int)f2bf(acc[c4*8+5]*s) << 16);
                pk.w = (unsigned int)f2bf(acc[c4*8+6]*s) | ((unsigned int)f2bf(acc[c4*8+7]*s) << 16);
                *reinterpret_cast<uint4*>(&As[sub][ln * 16 + c4 * 8]) = pk;
            }
        } else {
            uint4 z = make_uint4(0u, 0u, 0u, 0u);
            *reinterpret_cast<uint4*>(&As[sub][ln * 16]) = z;
            *reinterpret_cast<uint4*>(&As[sub][ln * 16 + 8]) = z;
        }
    }
    __syncthreads();

    const int lane = threadIdx.x & 63;
    const int wid  = threadIdx.x >> 6;
    const int wr   = wid >> 1, wc = wid & 1;
    const int fr   = lane & 15, fg = lane >> 4;

    f32x4 acc[4] = {};
    for (int k0 = 0; k0 < 128; k0 += 32) {
        short8v af = *reinterpret_cast<const short8v*>(&As[wr * 16 + fr][k0 + fg * 8]);
        #pragma unroll
        for (int n = 0; n < 4; ++n) {
            short8v bf = *reinterpret_cast<const short8v*>(
                rzwT + (size_t)(wc * 64 + n * 16 + fr) * 128 + k0 + fg * 8);
            acc[n] = __builtin_amdgcn_mfma_f32_16x16x32_bf16(af, bf, acc[n], 0, 0, 0);
        }
    }
    #pragma unroll
    for (int n = 0; n < 4; ++n) {
        int col = wc * 64 + n * 16 + fr;
        #pragma unroll
        for (int r = 0; r < 4; ++r) {
            int row = r0 + wr * 16 + fg * 4 + r;
            if (row < N_NODES) {
                float v = x[(size_t)row * 128 + col] + av * acc[n][r];
                h0b[(size_t)row * 128 + col] = f2bf(v);
            }
        }
    }
}

// ---------------------------------------------------------------------------
// Layer-3 GEMM (reordered): col<40 -> Pb bf16 (h2@w3); 40<=col<80 ->
// out f32 = h2@rw3 + b3.
// ---------------------------------------------------------------------------
__global__ __launch_bounds__(256) void gemm3(
    const unsigned short* __restrict__ A, const unsigned short* __restrict__ BT,
    const float* __restrict__ bias,
    unsigned short* __restrict__ Pb, float* __restrict__ outQ)
{
    constexpr int K = 256;
    __shared__ unsigned short As[64][40];
    __shared__ unsigned short Bs[64][40];
    const int tid  = threadIdx.x;
    const int lane = tid & 63;
    const int wid  = tid >> 6;
    const int fr   = lane & 15, fg = lane >> 4;
    const int bm   = blockIdx.x * 64;
    const int bn   = blockIdx.y * 64;

    f32x4 acc[4] = {};
    for (int k0 = 0; k0 < K; k0 += 32) {
        {
            int r = tid >> 2, kc = (tid & 3) * 8;
            int arow = bm + r;
            uint4 v = make_uint4(0u, 0u, 0u, 0u);
            if (arow < N_NODES)
                v = *reinterpret_cast<const uint4*>(A + (size_t)arow * K + k0 + kc);
            *reinterpret_cast<uint4*>(&As[r][kc]) = v;
            uint4 b = *reinterpret_cast<const uint4*>(BT + (size_t)(bn + r) * K + k0 + kc);
            *reinterpret_cast<uint4*>(&Bs[r][kc]) = b;
        }
        __syncthreads();
        short8v af = *reinterpret_cast<const short8v*>(&As[wid * 16 + fr][fg * 8]);
        #pragma unroll
        for (int n = 0; n < 4; ++n) {
            short8v bf = *reinterpret_cast<const short8v*>(&Bs[n * 16 + fr][fg * 8]);
            acc[n] = __builtin_amdgcn_mfma_f32_16x16x32_bf16(af, bf, acc[n], 0, 0, 0);
        }
        __syncthreads();
    }
    #pragma unroll
    for (int n = 0; n < 4; ++n) {
        int col = bn + n * 16 + fr;
        #pragma unroll
        for (int r = 0; r < 4; ++r) {
            int row = bm + wid * 16 + fg * 4 + r;
            if (row >= N_NODES) continue;
            float v = acc[n][r];
            if (col < 40)      Pb[(size_t)row * 40 + col] = f2bf(v);
            else if (col < 80) outQ[(size_t)row * 40 + (col - 40)] = v + bias[col - 40];
        }
    }
}

// ---------------------------------------------------------------------------
// Final L3 aggregation with LDS-staged edges:
// out[row,0:40] += deg^-1.5 * sum_j dis_j * Pb[j,:]
// ---------------------------------------------------------------------------
__global__ __launch_bounds__(256) void agg_add40(
    const unsigned short* __restrict__ Pb,
    const int* __restrict__ ell, const int* __restrict__ cnt,
    float* __restrict__ out)
{
    __shared__ int   sj[8][KMAX];
    __shared__ float sw[8][KMAX];
    const int sub = threadIdx.x >> 5;
    const int ln  = threadIdx.x & 31;
    const int row = blockIdx.x * 8 + sub;

    int len = 1;
    if (row < N_NODES) {
        len = cnt[row]; if (len > KMAX) len = KMAX; if (len < 1) len = 1;
        const int* el = ell + (size_t)row * KMAX;
        for (int e = ln; e < len; e += 32) {
            int j = el[e];
            int d = cnt[j]; if (d > KMAX) d = KMAX; if (d < 1) d = 1;
            sj[sub][e] = j;
            sw[sub][e] = rsqrtf((float)d);
        }
    }
    __syncthreads();
    if (row >= N_NODES || ln >= 10) return;

    float a0 = 0.0f, a1 = 0.0f, a2 = 0.0f, a3 = 0.0f;
    #pragma unroll 4
    for (int e = 0; e < len; ++e) {
        int   j = sj[sub][e];
        float w = sw[sub][e];
        uint2 u = *reinterpret_cast<const uint2*>(Pb + (size_t)j * 40 + 4 * ln);
        a0 += w * bflo(u.x);
        a1 += w * bfhi(u.x);
        a2 += w * bflo(u.y);
        a3 += w * bfhi(u.y);
    }
    float fd = (float)len;
    float s = rsqrtf(fd) / fd;
    float4* op = reinterpret_cast<float4*>(out + (size_t)row * 40 + 4 * ln);
    float4 v = *op;
    v.x += a0 * s; v.y += a1 * s; v.z += a2 * s; v.w += a3 * s;
    *op = v;
}

extern "C" void kernel_launch(void* const* d_in, const int* in_sizes, int n_in,
                              void* d_out, int out_size, void* d_ws, size_t ws_size,
                              hipStream_t stream)
{
    (void)in_sizes; (void)n_in; (void)out_size; (void)ws_size;
    const float* x     = (const float*)d_in[0];
    const float* adj   = (const float*)d_in[1];
    const float* alpha = (const float*)d_in[2];
    const float* b1    = (const float*)d_in[6];
    const float* b2    = (const float*)d_in[9];
    const float* b3    = (const float*)d_in[12];
    float* out = (float*)d_out;

    char* ws = (char*)d_ws;
    size_t off = 0;
    auto alloc = [&](size_t bytes) -> char* {
        char* q = ws + off;
        off = (off + bytes + 255) & ~(size_t)255;
        return q;
    };
    int*            cnt  = (int*)  alloc((size_t)N_NODES * 4);
    int*            ell  = (int*)  alloc((size_t)N_NODES * KMAX * 4);
    unsigned short* xb   = (unsigned short*)alloc((size_t)N_NODES * 128 * 2);
    unsigned short* h0b  = (unsigned short*)alloc((size_t)N_NODES * 128 * 2);
    unsigned short* h1b  = (unsigned short*)alloc((size_t)N_NODES * 256 * 2);
    unsigned short* h2b  = (unsigned short*)alloc((size_t)N_NODES * 256 * 2);
    unsigned short* Pb   = (unsigned short*)alloc((size_t)N_NODES * 40 * 2);
    unsigned short* rzwT = (unsigned short*)alloc((size_t)128 * 128 * 2);
    unsigned short* w1T  = (unsigned short*)alloc((size_t)256 * 256 * 2);
    unsigned short* w2T  = (unsigned short*)alloc((size_t)256 * 512 * 2);
    unsigned short* w3T  = (unsigned short*)alloc((size_t)128 * 256 * 2);

    Prm p;
    p.x = x; p.rzw = (const float*)d_in[3];
    p.w1 = (const float*)d_in[4]; p.rw1 = (const float*)d_in[5];
    p.w2 = (const float*)d_in[7]; p.rw2 = (const float*)d_in[8];
    p.w3 = (const float*)d_in[10]; p.rw3 = (const float*)d_in[11];
    p.xb = xb; p.rzwT = rzwT; p.w1T = w1T; p.w2T = w2T; p.w3T = w3T;

    zero_cnt<<<(N_NODES + 255) / 256, 256, 0, stream>>>(cnt);
    prep_scan<<<N_NODES / 2, 256, 0, stream>>>(p, adj, ell, cnt);
    rz_fused<<<(N_NODES + 31) / 32, 256, 0, stream>>>(xb, x, ell, cnt, rzwT, alpha, h0b);
    layer_fused<128><<<(N_NODES + 15) / 16, 256, 0, stream>>>(xb, h0b, alpha, ell, cnt, w1T, b1, h1b);
    layer_fused<256><<<(N_NODES + 15) / 16, 256, 0, stream>>>(h1b, h1b, nullptr, ell, cnt, w2T, b2, h2b);
    gemm3<<<dim3((N_NODES + 63) / 64, 2), 256, 0, stream>>>(h2b, w3T, b3, Pb, out);
    agg_add40<<<(N_NODES + 7) / 8, 256, 0, stream>>>(Pb, ell, cnt, out);
}

// Round 11
// 136.907 us; speedup vs baseline: 1.1017x; 1.0257x over previous
//
#include <hip/hip_runtime.h>

#define N_NODES 10000
#define KMAX    128
#define PREP_TOT (640000 + 16384 + 65536 + 131072 + 32768)   // = 885760

typedef __attribute__((ext_vector_type(8))) short short8v;
typedef __attribute__((ext_vector_type(4))) float f32x4;

__device__ inline unsigned short f2bf(float f) {
    unsigned int u = __float_as_uint(f);
    return (unsigned short)((u + 0x7fffu + ((u >> 16) & 1u)) >> 16);
}
__device__ inline float bflo(unsigned int u) { return __uint_as_float(u << 16); }
__device__ inline float bfhi(unsigned int u) { return __uint_as_float(u & 0xffff0000u); }

struct Prm {
    const float *x, *rzw, *w1, *rw1, *w2, *rw2, *w3, *rw3;
    unsigned short *xb, *rzwT, *w1T, *w2T, *w3T;
};

__global__ __launch_bounds__(256) void zero_cnt(int* __restrict__ cnt)
{
    int i = blockIdx.x * 256 + threadIdx.x;
    if (i < N_NODES) cnt[i] = 0;
}

// ---------------------------------------------------------------------------
// Prep work distributor (x -> xb bf16; weights -> bf16 [n][k] concat/merge).
// ---------------------------------------------------------------------------
__device__ inline void do_prep(int i, const Prm& p)
{
    if (i < 640000) {
        float2 v = reinterpret_cast<const float2*>(p.x)[i];
        unsigned int pk = (unsigned int)f2bf(v.x) | ((unsigned int)f2bf(v.y) << 16);
        int row = i >> 6, c = (i & 63) * 2;
        *reinterpret_cast<unsigned int*>(p.xb + (size_t)row * 128 + c) = pk;
        return;
    }
    i -= 640000;
    if (i < 16384) { int n = i >> 7, k = i & 127; p.rzwT[i] = f2bf(p.rzw[k * 128 + n]); return; }
    i -= 16384;
    if (i < 65536) {
        int n = i >> 8, k = i & 255;
        p.w1T[i] = f2bf((k < 128) ? p.w1[k * 256 + n] : p.rw1[(k - 128) * 256 + n]);
        return;
    }
    i -= 65536;
    if (i < 131072) {
        int n = i >> 9, k = i & 511;
        p.w2T[i] = f2bf((k < 256) ? p.w2[k * 256 + n] : p.rw2[(k - 256) * 256 + n]);
        return;
    }
    i -= 131072;
    {
        int n = i >> 8, k = i & 255;
        float v = 0.0f;
        if (n < 40)      v = p.w3[k * 40 + n];
        else if (n < 80) v = p.rw3[k * 40 + (n - 40)];
        p.w3T[i] = f2bf(v);
    }
}

// ---------------------------------------------------------------------------
// Fused prep + balanced symmetric half-scan: block b scans rows b and
// 9999-b (j >= row each) -> every block reads ~40 KB.
// ---------------------------------------------------------------------------
__global__ __launch_bounds__(256) void prep_scan(
    Prm p, const float* __restrict__ adj, int* __restrict__ ell, int* __restrict__ cnt)
{
    int gi = blockIdx.x * 256 + threadIdx.x;
    if (gi < PREP_TOT) do_prep(gi, p);

    const int rows[2] = { (int)blockIdx.x, N_NODES - 1 - (int)blockIdx.x };
    #pragma unroll
    for (int t = 0; t < 2; ++t) {
        int row = rows[t];
        const float4* rp = reinterpret_cast<const float4*>(adj + (size_t)row * N_NODES);
        for (int f = (row >> 2) + threadIdx.x; f < N_NODES / 4; f += 256) {
            float4 v = rp[f];
            int base = f * 4;
            #pragma unroll
            for (int s = 0; s < 4; ++s) {
                float e = (s == 0) ? v.x : (s == 1) ? v.y : (s == 2) ? v.z : v.w;
                int j = base + s;
                if (e != 0.0f && j >= row) {
                    int q = atomicAdd(&cnt[row], 1);
                    if (q < KMAX) ell[(size_t)row * KMAX + q] = j;
                    if (j > row) {
                        int q2 = atomicAdd(&cnt[j], 1);
                        if (q2 < KMAX) ell[(size_t)j * KMAX + q2] = row;
                    }
                }
            }
        }
    }
}

// ---------------------------------------------------------------------------
// Fused layer, 512-thread blocks (8 waves): 16-row slab per block, 625 blocks
// (10000 = 625*16, no tail). Phase A: LDS-staged edges (32 lanes/row), then
// gather-agg (CIN/32 channels/lane, unroll 4) + h-copy -> LDS [agg | h].
// Phase B: 16-row x 256-col MFMA GEMM, 8 waves x 32 cols, K=2*CIN, B-frags
// direct from L2-hot BT. bias+relu, bf16 out (stride 256).
// Per-channel accumulation order identical to R10 -> bit-identical output.
// ---------------------------------------------------------------------------
template<int CIN>
__global__ __launch_bounds__(512) void layer_fused(
    const unsigned short* __restrict__ src0,   // alpha==0 gather/h source
    const unsigned short* __restrict__ src1,   // alpha!=0 source (h0b)
    const float* __restrict__ alpha,           // null => always src0
    const int* __restrict__ ell, const int* __restrict__ cnt,
    const unsigned short* __restrict__ BT,
    const float* __restrict__ bias,
    unsigned short* __restrict__ outB)
{
    const unsigned short* hb = (alpha && alpha[0] != 0.0f) ? src1 : src0;
    constexpr int K   = 2 * CIN;
    constexpr int LDA = K + 8;
    constexpr int CPL = CIN / 32;              // channels per lane (4 or 8)
    __shared__ unsigned short As[16][LDA];
    __shared__ int   sj[16][KMAX];
    __shared__ float sw[16][KMAX];
    const int r0  = blockIdx.x * 16;
    const int sub = threadIdx.x >> 5;          // slab row 0..15
    const int ln  = threadIdx.x & 31;          // 32 lanes per row
    const int row = r0 + sub;                  // always < N_NODES (625*16)

    int len = cnt[row]; if (len > KMAX) len = KMAX; if (len < 1) len = 1;
    {
        const int* el = ell + (size_t)row * KMAX;
        for (int e = ln; e < len; e += 32) {
            int j = el[e];
            int d = cnt[j]; if (d > KMAX) d = KMAX; if (d < 1) d = 1;
            sj[sub][e] = j;
            sw[sub][e] = rsqrtf((float)d);
        }
    }
    __syncthreads();

    {
        float acc[CPL] = {};
        #pragma unroll 4
        for (int e = 0; e < len; ++e) {
            int   j = sj[sub][e];
            float w = sw[sub][e];
            if constexpr (CPL == 4) {
                uint2 u = *reinterpret_cast<const uint2*>(hb + (size_t)j * CIN + ln * 4);
                acc[0] += w * bflo(u.x); acc[1] += w * bfhi(u.x);
                acc[2] += w * bflo(u.y); acc[3] += w * bfhi(u.y);
            } else {
                uint4 u = *reinterpret_cast<const uint4*>(hb + (size_t)j * CIN + ln * 8);
                acc[0] += w * bflo(u.x); acc[1] += w * bfhi(u.x);
                acc[2] += w * bflo(u.y); acc[3] += w * bfhi(u.y);
                acc[4] += w * bflo(u.z); acc[5] += w * bfhi(u.z);
                acc[6] += w * bflo(u.w); acc[7] += w * bfhi(u.w);
            }
        }
        float fd = (float)len;
        float s  = rsqrtf(fd) / fd;            // dis_i * invn_i (mean agg)
        if constexpr (CPL == 4) {
            uint2 pk;
            pk.x = (unsigned int)f2bf(acc[0]*s) | ((unsigned int)f2bf(acc[1]*s) << 16);
            pk.y = (unsigned int)f2bf(acc[2]*s) | ((unsigned int)f2bf(acc[3]*s) << 16);
            *reinterpret_cast<uint2*>(&As[sub][ln * 4]) = pk;
            uint2 h = *reinterpret_cast<const uint2*>(hb + (size_t)row * CIN + ln * 4);
            *reinterpret_cast<uint2*>(&As[sub][CIN + ln * 4]) = h;
        } else {
            uint4 pk;
            pk.x = (unsigned int)f2bf(acc[0]*s) | ((unsigned int)f2bf(acc[1]*s) << 16);
            pk.y = (unsigned int)f2bf(acc[2]*s) | ((unsigned int)f2bf(acc[3]*s) << 16);
            pk.z = (unsigned int)f2bf(acc[4]*s) | ((unsigned int)f2bf(acc[5]*s) << 16);
            pk.w = (unsigned int)f2bf(acc[6]*s) | ((unsigned int)f2bf(acc[7]*s) << 16);
            *reinterpret_cast<uint4*>(&As[sub][ln * 8]) = pk;
            uint4 h = *reinterpret_cast<const uint4*>(hb + (size_t)row * CIN + ln * 8);
            *reinterpret_cast<uint4*>(&As[sub][CIN + ln * 8]) = h;
        }
    }
    __syncthreads();

    // ---- Phase B: 16 rows x 256 cols, 8 waves x 32 cols -------------------
    const int lane = threadIdx.x & 63;
    const int wid  = threadIdx.x >> 6;         // wave 0..7 -> cols [wid*32,+32)
    const int fr   = lane & 15, fg = lane >> 4;
    const int bn   = wid * 32;

    f32x4 acc4[2] = {};
    for (int k0 = 0; k0 < K; k0 += 32) {
        short8v af = *reinterpret_cast<const short8v*>(&As[fr][k0 + fg * 8]);
        #pragma unroll
        for (int n = 0; n < 2; ++n) {
            short8v bf = *reinterpret_cast<const short8v*>(
                BT + (size_t)(bn + n * 16 + fr) * K + k0 + fg * 8);
            acc4[n] = __builtin_amdgcn_mfma_f32_16x16x32_bf16(af, bf, acc4[n], 0, 0, 0);
        }
    }

    // C/D layout: col = lane&15, row = 4*(lane>>4)+reg  [HW-verified]
    #pragma unroll
    for (int n = 0; n < 2; ++n) {
        int col = bn + n * 16 + fr;
        #pragma unroll
        for (int r = 0; r < 4; ++r) {
            int orow = r0 + fg * 4 + r;
            float v = fmaxf(acc4[n][r] + bias[col], 0.0f);
            outB[(size_t)orow * 256 + col] = f2bf(v);
        }
    }
}

// ---------------------------------------------------------------------------
// Fused rezero (gated no-op when alpha==0): agg(x)@rzwT, h0 = x + a*acc.
// ---------------------------------------------------------------------------
__global__ __launch_bounds__(256) void rz_fused(
    const unsigned short* __restrict__ xb, const float* __restrict__ x,
    const int* __restrict__ ell, const int* __restrict__ cnt,
    const unsigned short* __restrict__ rzwT,
    const float* __restrict__ alpha,
    unsigned short* __restrict__ h0b)
{
    float av = alpha[0];
    if (av == 0.0f) return;
    __shared__ unsigned short As[32][136];
    const int r0 = blockIdx.x * 32;
    {
        const int sub = threadIdx.x >> 3;
        const int ln  = threadIdx.x & 7;
        const int row = r0 + sub;
        if (row < N_NODES) {
            int len = cnt[row]; if (len > KMAX) len = KMAX; if (len < 1) len = 1;
            const int* el = ell + (size_t)row * KMAX;
            float acc[16] = {};
            #pragma unroll 2
            for (int e = 0; e < len; ++e) {
                int j = el[e];
                int d = cnt[j]; if (d > KMAX) d = KMAX; if (d < 1) d = 1;
                float w = rsqrtf((float)d);
                const uint4* srcp = reinterpret_cast<const uint4*>(xb + (size_t)j * 128 + ln * 16);
                #pragma unroll
                for (int c4 = 0; c4 < 2; ++c4) {
                    uint4 u = srcp[c4];
                    acc[c4*8+0] += w * bflo(u.x); acc[c4*8+1] += w * bfhi(u.x);
                    acc[c4*8+2] += w * bflo(u.y); acc[c4*8+3] += w * bfhi(u.y);
                    acc[c4*8+4] += w * bflo(u.z); acc[c4*8+5] += w * bfhi(u.z);
                    acc[c4*8+6] += w * bflo(u.w); acc[c4*8+7] += w * bfhi(u.w);
                }
            }
            float s = rsqrtf((float)len);
            #pragma unroll
            for (int c4 = 0; c4 < 2; ++c4) {
                uint4 pk;
                pk.x = (unsigned int)f2bf(acc[c4*8+0]*s) | ((unsigned int)f2bf(acc[c4*8+1]*s) << 16);
                pk.y = (unsigned int)f2bf(acc[c4*8+2]*s) | ((unsigned int)f2bf(acc[c4*8+3]*s) << 16);
                pk.z = (unsigned int)f2bf(acc[c4*8+4]*s) | ((unsigned int)f2bf(acc[c4*8+5]*s) << 16);
                pk.w = (unsigned int)f2bf(acc[c4*8+6]*s) | ((unsigned int)f2bf(acc[c4*8+7]*s) << 16);
                *reinterpret_cast<uint4*>(&As[sub][ln * 16 + c4 * 8]) = pk;
            }
        } else {
            uint4 z = make_uint4(0u, 0u, 0u, 0u);
            *reinterpret_cast<uint4*>(&As[sub][ln * 16]) = z;
            *reinterpret_cast<uint4*>(&As[sub][ln * 16 + 8]) = z;
        }
    }
    __syncthreads();

    const int lane = threadIdx.x & 63;
    const int wid  = threadIdx.x >> 6;
    const int wr   = wid >> 1, wc = wid & 1;
    const int fr   = lane & 15, fg = lane >> 4;

    f32x4 acc[4] = {};
    for (int k0 = 0; k0 < 128; k0 += 32) {
        short8v af = *reinterpret_cast<const short8v*>(&As[wr * 16 + fr][k0 + fg * 8]);
        #pragma unroll
        for (int n = 0; n < 4; ++n) {
            short8v bf = *reinterpret_cast<const short8v*>(
                rzwT + (size_t)(wc * 64 + n * 16 + fr) * 128 + k0 + fg * 8);
            acc[n] = __builtin_amdgcn_mfma_f32_16x16x32_bf16(af, bf, acc[n], 0, 0, 0);
        }
    }
    #pragma unroll
    for (int n = 0; n < 4; ++n) {
        int col = wc * 64 + n * 16 + fr;
        #pragma unroll
        for (int r = 0; r < 4; ++r) {
            int row = r0 + wr * 16 + fg * 4 + r;
            if (row < N_NODES) {
                float v = x[(size_t)row * 128 + col] + av * acc[n][r];
                h0b[(size_t)row * 128 + col] = f2bf(v);
            }
        }
    }
}

// ---------------------------------------------------------------------------
// Layer-3 GEMM (reordered): col<40 -> Pb bf16 (h2@w3); 40<=col<80 ->
// out f32 = h2@rw3 + b3.
// ---------------------------------------------------------------------------
__global__ __launch_bounds__(256) void gemm3(
    const unsigned short* __restrict__ A, const unsigned short* __restrict__ BT,
    const float* __restrict__ bias,
    unsigned short* __restrict__ Pb, float* __restrict__ outQ)
{
    constexpr int K = 256;
    __shared__ unsigned short As[64][40];
    __shared__ unsigned short Bs[64][40];
    const int tid  = threadIdx.x;
    const int lane = tid & 63;
    const int wid  = tid >> 6;
    const int fr   = lane & 15, fg = lane >> 4;
    const int bm   = blockIdx.x * 64;
    const int bn   = blockIdx.y * 64;

    f32x4 acc[4] = {};
    for (int k0 = 0; k0 < K; k0 += 32) {
        {
            int r = tid >> 2, kc = (tid & 3) * 8;
            int arow = bm + r;
            uint4 v = make_uint4(0u, 0u, 0u, 0u);
            if (arow < N_NODES)
                v = *reinterpret_cast<const uint4*>(A + (size_t)arow * K + k0 + kc);
            *reinterpret_cast<uint4*>(&As[r][kc]) = v;
            uint4 b = *reinterpret_cast<const uint4*>(BT + (size_t)(bn + r) * K + k0 + kc);
            *reinterpret_cast<uint4*>(&Bs[r][kc]) = b;
        }
        __syncthreads();
        short8v af = *reinterpret_cast<const short8v*>(&As[wid * 16 + fr][fg * 8]);
        #pragma unroll
        for (int n = 0; n < 4; ++n) {
            short8v bf = *reinterpret_cast<const short8v*>(&Bs[n * 16 + fr][fg * 8]);
            acc[n] = __builtin_amdgcn_mfma_f32_16x16x32_bf16(af, bf, acc[n], 0, 0, 0);
        }
        __syncthreads();
    }
    #pragma unroll
    for (int n = 0; n < 4; ++n) {
        int col = bn + n * 16 + fr;
        #pragma unroll
        for (int r = 0; r < 4; ++r) {
            int row = bm + wid * 16 + fg * 4 + r;
            if (row >= N_NODES) continue;
            float v = acc[n][r];
            if (col < 40)      Pb[(size_t)row * 40 + col] = f2bf(v);
            else if (col < 80) outQ[(size_t)row * 40 + (col - 40)] = v + bias[col - 40];
        }
    }
}

// ---------------------------------------------------------------------------
// Final L3 aggregation with LDS-staged edges:
// out[row,0:40] += deg^-1.5 * sum_j dis_j * Pb[j,:]
// ---------------------------------------------------------------------------
__global__ __launch_bounds__(256) void agg_add40(
    const unsigned short* __restrict__ Pb,
    const int* __restrict__ ell, const int* __restrict__ cnt,
    float* __restrict__ out)
{
    __shared__ int   sj[8][KMAX];
    __shared__ float sw[8][KMAX];
    const int sub = threadIdx.x >> 5;
    const int ln  = threadIdx.x & 31;
    const int row = blockIdx.x * 8 + sub;

    int len = 1;
    if (row < N_NODES) {
        len = cnt[row]; if (len > KMAX) len = KMAX; if (len < 1) len = 1;
        const int* el = ell + (size_t)row * KMAX;
        for (int e = ln; e < len; e += 32) {
            int j = el[e];
            int d = cnt[j]; if (d > KMAX) d = KMAX; if (d < 1) d = 1;
            sj[sub][e] = j;
            sw[sub][e] = rsqrtf((float)d);
        }
    }
    __syncthreads();
    if (row >= N_NODES || ln >= 10) return;

    float a0 = 0.0f, a1 = 0.0f, a2 = 0.0f, a3 = 0.0f;
    #pragma unroll 4
    for (int e = 0; e < len; ++e) {
        int   j = sj[sub][e];
        float w = sw[sub][e];
        uint2 u = *reinterpret_cast<const uint2*>(Pb + (size_t)j * 40 + 4 * ln);
        a0 += w * bflo(u.x);
        a1 += w * bfhi(u.x);
        a2 += w * bflo(u.y);
        a3 += w * bfhi(u.y);
    }
    float fd = (float)len;
    float s = rsqrtf(fd) / fd;
    float4* op = reinterpret_cast<float4*>(out + (size_t)row * 40 + 4 * ln);
    float4 v = *op;
    v.x += a0 * s; v.y += a1 * s; v.z += a2 * s; v.w += a3 * s;
    *op = v;
}

extern "C" void kernel_launch(void* const* d_in, const int* in_sizes, int n_in,
                              void* d_out, int out_size, void* d_ws, size_t ws_size,
                              hipStream_t stream)
{
    (void)in_sizes; (void)n_in; (void)out_size; (void)ws_size;
    const float* x     = (const float*)d_in[0];
    const float* adj   = (const float*)d_in[1];
    const float* alpha = (const float*)d_in[2];
    const float* b1    = (const float*)d_in[6];
    const float* b2    = (const float*)d_in[9];
    const float* b3    = (const float*)d_in[12];
    float* out = (float*)d_out;

    char* ws = (char*)d_ws;
    size_t off = 0;
    auto alloc = [&](size_t bytes) -> char* {
        char* q = ws + off;
        off = (off + bytes + 255) & ~(size_t)255;
        return q;
    };
    int*            cnt  = (int*)  alloc((size_t)N_NODES * 4);
    int*            ell  = (int*)  alloc((size_t)N_NODES * KMAX * 4);
    unsigned short* xb   = (unsigned short*)alloc((size_t)N_NODES * 128 * 2);
    unsigned short* h0b  = (unsigned short*)alloc((size_t)N_NODES * 128 * 2);
    unsigned short* h1b  = (unsigned short*)alloc((size_t)N_NODES * 256 * 2);
    unsigned short* h2b  = (unsigned short*)alloc((size_t)N_NODES * 256 * 2);
    unsigned short* Pb   = (unsigned short*)alloc((size_t)N_NODES * 40 * 2);
    unsigned short* rzwT = (unsigned short*)alloc((size_t)128 * 128 * 2);
    unsigned short* w1T  = (unsigned short*)alloc((size_t)256 * 256 * 2);
    unsigned short* w2T  = (unsigned short*)alloc((size_t)256 * 512 * 2);
    unsigned short* w3T  = (unsigned short*)alloc((size_t)128 * 256 * 2);

    Prm p;
    p.x = x; p.rzw = (const float*)d_in[3];
    p.w1 = (const float*)d_in[4]; p.rw1 = (const float*)d_in[5];
    p.w2 = (const float*)d_in[7]; p.rw2 = (const float*)d_in[8];
    p.w3 = (const float*)d_in[10]; p.rw3 = (const float*)d_in[11];
    p.xb = xb; p.rzwT = rzwT; p.w1T = w1T; p.w2T = w2T; p.w3T = w3T;

    zero_cnt<<<(N_NODES + 255) / 256, 256, 0, stream>>>(cnt);
    prep_scan<<<N_NODES / 2, 256, 0, stream>>>(p, adj, ell, cnt);
    rz_fused<<<(N_NODES + 31) / 32, 256, 0, stream>>>(xb, x, ell, cnt, rzwT, alpha, h0b);
    layer_fused<128><<<N_NODES / 16, 512, 0, stream>>>(xb, h0b, alpha, ell, cnt, w1T, b1, h1b);
    layer_fused<256><<<N_NODES / 16, 512, 0, stream>>>(h1b, h1b, nullptr, ell, cnt, w2T, b2, h2b);
    gemm3<<<dim3((N_NODES + 63) / 64, 2), 256, 0, stream>>>(h2b, w3T, b3, Pb, out);
    agg_add40<<<(N_NODES + 7) / 8, 256, 0, stream>>>(Pb, ell, cnt, out);
}

// Round 12
// 131.791 us; speedup vs baseline: 1.1445x; 1.0388x over previous
//
#include <hip/hip_runtime.h>

#define N_NODES 10000
#define KMAX    128
#define PREP_TOT (640000 + 16384 + 65536 + 131072 + 32768)   // = 885760

typedef __attribute__((ext_vector_type(8))) short short8v;
typedef __attribute__((ext_vector_type(4))) float f32x4;

__device__ inline unsigned short f2bf(float f) {
    unsigned int u = __float_as_uint(f);
    return (unsigned short)((u + 0x7fffu + ((u >> 16) & 1u)) >> 16);
}
__device__ inline float bflo(unsigned int u) { return __uint_as_float(u << 16); }
__device__ inline float bfhi(unsigned int u) { return __uint_as_float(u & 0xffff0000u); }

struct Prm {
    const float *x, *rzw, *w1, *rw1, *w2, *rw2, *w3, *rw3;
    unsigned short *xb, *rzwT, *w1T, *w2T, *w3T;
};

__global__ __launch_bounds__(256) void zero_cnt(int* __restrict__ cnt)
{
    int i = blockIdx.x * 256 + threadIdx.x;
    if (i < N_NODES) cnt[i] = 0;
}

// ---------------------------------------------------------------------------
// Prep work distributor (x -> xb bf16; weights -> bf16 [n][k] concat/merge).
// ---------------------------------------------------------------------------
__device__ inline void do_prep(int i, const Prm& p)
{
    if (i < 640000) {
        float2 v = reinterpret_cast<const float2*>(p.x)[i];
        unsigned int pk = (unsigned int)f2bf(v.x) | ((unsigned int)f2bf(v.y) << 16);
        int row = i >> 6, c = (i & 63) * 2;
        *reinterpret_cast<unsigned int*>(p.xb + (size_t)row * 128 + c) = pk;
        return;
    }
    i -= 640000;
    if (i < 16384) { int n = i >> 7, k = i & 127; p.rzwT[i] = f2bf(p.rzw[k * 128 + n]); return; }
    i -= 16384;
    if (i < 65536) {
        int n = i >> 8, k = i & 255;
        p.w1T[i] = f2bf((k < 128) ? p.w1[k * 256 + n] : p.rw1[(k - 128) * 256 + n]);
        return;
    }
    i -= 65536;
    if (i < 131072) {
        int n = i >> 9, k = i & 511;
        p.w2T[i] = f2bf((k < 256) ? p.w2[k * 256 + n] : p.rw2[(k - 256) * 256 + n]);
        return;
    }
    i -= 131072;
    {
        int n = i >> 8, k = i & 255;
        float v = 0.0f;
        if (n < 40)      v = p.w3[k * 40 + n];
        else if (n < 80) v = p.rw3[k * 40 + (n - 40)];
        p.w3T[i] = f2bf(v);
    }
}

// ---------------------------------------------------------------------------
// Fused prep + balanced symmetric half-scan: block b scans rows b and
// 9999-b (j >= row each) -> every block reads ~40 KB.
// ---------------------------------------------------------------------------
__global__ __launch_bounds__(256) void prep_scan(
    Prm p, const float* __restrict__ adj, int* __restrict__ ell, int* __restrict__ cnt)
{
    int gi = blockIdx.x * 256 + threadIdx.x;
    if (gi < PREP_TOT) do_prep(gi, p);

    const int rows[2] = { (int)blockIdx.x, N_NODES - 1 - (int)blockIdx.x };
    #pragma unroll
    for (int t = 0; t < 2; ++t) {
        int row = rows[t];
        const float4* rp = reinterpret_cast<const float4*>(adj + (size_t)row * N_NODES);
        for (int f = (row >> 2) + threadIdx.x; f < N_NODES / 4; f += 256) {
            float4 v = rp[f];
            int base = f * 4;
            #pragma unroll
            for (int s = 0; s < 4; ++s) {
                float e = (s == 0) ? v.x : (s == 1) ? v.y : (s == 2) ? v.z : v.w;
                int j = base + s;
                if (e != 0.0f && j >= row) {
                    int q = atomicAdd(&cnt[row], 1);
                    if (q < KMAX) ell[(size_t)row * KMAX + q] = j;
                    if (j > row) {
                        int q2 = atomicAdd(&cnt[j], 1);
                        if (q2 < KMAX) ell[(size_t)j * KMAX + q2] = row;
                    }
                }
            }
        }
    }
}

// ---------------------------------------------------------------------------
// Fused layer, 512-thread blocks (8 waves), 16-row slab per block, 625 blocks
// (10000 = 625*16, no tails).
//  Phase A: LDS-staged edges (32 lanes/row), gather-agg + h-copy -> LDS [agg|h]
//  Phase B: 16x256 MFMA GEMM, 8 waves x 32 cols, K=2*CIN, B direct from BT.
//  FUSE3=false: bias+relu -> bf16 outB (stride 256).
//  FUSE3=true (layer 2+3): h2 = relu(.+bias) kept in LDS only; Phase C:
//    waves 0-4 compute [P|Q] = h2 @ [w3|rw3] (K=256); col<40 -> Pb bf16,
//    40<=col<80 -> outQ f32 + b3. Eliminates the separate gemm3 kernel and
//    all h2 global traffic. MFMA sequence identical -> bit-identical output.
// ---------------------------------------------------------------------------
template<int CIN, bool FUSE3>
__global__ __launch_bounds__(512) void layer_fused(
    const unsigned short* __restrict__ src0,   // alpha==0 gather/h source
    const unsigned short* __restrict__ src1,   // alpha!=0 source (h0b)
    const float* __restrict__ alpha,           // null => always src0
    const int* __restrict__ ell, const int* __restrict__ cnt,
    const unsigned short* __restrict__ BT,
    const float* __restrict__ bias,
    unsigned short* __restrict__ outB,
    const unsigned short* __restrict__ w3T, const float* __restrict__ b3,
    unsigned short* __restrict__ Pb, float* __restrict__ outQ)
{
    const unsigned short* hb = (alpha && alpha[0] != 0.0f) ? src1 : src0;
    constexpr int K   = 2 * CIN;
    constexpr int LDA = K + 8;
    constexpr int CPL = CIN / 32;              // channels per lane (4 or 8)
    __shared__ unsigned short As[16][LDA];
    __shared__ int   sj[16][KMAX];
    __shared__ float sw[16][KMAX];
    const int r0  = blockIdx.x * 16;
    const int sub = threadIdx.x >> 5;          // slab row 0..15
    const int ln  = threadIdx.x & 31;          // 32 lanes per row
    const int row = r0 + sub;                  // always < N_NODES

    int len = cnt[row]; if (len > KMAX) len = KMAX; if (len < 1) len = 1;
    {
        const int* el = ell + (size_t)row * KMAX;
        for (int e = ln; e < len; e += 32) {
            int j = el[e];
            int d = cnt[j]; if (d > KMAX) d = KMAX; if (d < 1) d = 1;
            sj[sub][e] = j;
            sw[sub][e] = rsqrtf((float)d);
        }
    }
    __syncthreads();

    {
        float acc[CPL] = {};
        #pragma unroll 4
        for (int e = 0; e < len; ++e) {
            int   j = sj[sub][e];
            float w = sw[sub][e];
            if constexpr (CPL == 4) {
                uint2 u = *reinterpret_cast<const uint2*>(hb + (size_t)j * CIN + ln * 4);
                acc[0] += w * bflo(u.x); acc[1] += w * bfhi(u.x);
                acc[2] += w * bflo(u.y); acc[3] += w * bfhi(u.y);
            } else {
                uint4 u = *reinterpret_cast<const uint4*>(hb + (size_t)j * CIN + ln * 8);
                acc[0] += w * bflo(u.x); acc[1] += w * bfhi(u.x);
                acc[2] += w * bflo(u.y); acc[3] += w * bfhi(u.y);
                acc[4] += w * bflo(u.z); acc[5] += w * bfhi(u.z);
                acc[6] += w * bflo(u.w); acc[7] += w * bfhi(u.w);
            }
        }
        float fd = (float)len;
        float s  = rsqrtf(fd) / fd;            // dis_i * invn_i (mean agg)
        if constexpr (CPL == 4) {
            uint2 pk;
            pk.x = (unsigned int)f2bf(acc[0]*s) | ((unsigned int)f2bf(acc[1]*s) << 16);
            pk.y = (unsigned int)f2bf(acc[2]*s) | ((unsigned int)f2bf(acc[3]*s) << 16);
            *reinterpret_cast<uint2*>(&As[sub][ln * 4]) = pk;
            uint2 h = *reinterpret_cast<const uint2*>(hb + (size_t)row * CIN + ln * 4);
            *reinterpret_cast<uint2*>(&As[sub][CIN + ln * 4]) = h;
        } else {
            uint4 pk;
            pk.x = (unsigned int)f2bf(acc[0]*s) | ((unsigned int)f2bf(acc[1]*s) << 16);
            pk.y = (unsigned int)f2bf(acc[2]*s) | ((unsigned int)f2bf(acc[3]*s) << 16);
            pk.z = (unsigned int)f2bf(acc[4]*s) | ((unsigned int)f2bf(acc[5]*s) << 16);
            pk.w = (unsigned int)f2bf(acc[6]*s) | ((unsigned int)f2bf(acc[7]*s) << 16);
            *reinterpret_cast<uint4*>(&As[sub][ln * 8]) = pk;
            uint4 h = *reinterpret_cast<const uint4*>(hb + (size_t)row * CIN + ln * 8);
            *reinterpret_cast<uint4*>(&As[sub][CIN + ln * 8]) = h;
        }
    }
    __syncthreads();

    // ---- Phase B: 16 rows x 256 cols, 8 waves x 32 cols -------------------
    const int lane = threadIdx.x & 63;
    const int wid  = threadIdx.x >> 6;         // wave 0..7 -> cols [wid*32,+32)
    const int fr   = lane & 15, fg = lane >> 4;
    const int bn   = wid * 32;

    f32x4 acc4[2] = {};
    for (int k0 = 0; k0 < K; k0 += 32) {
        short8v af = *reinterpret_cast<const short8v*>(&As[fr][k0 + fg * 8]);
        #pragma unroll
        for (int n = 0; n < 2; ++n) {
            short8v bf = *reinterpret_cast<const short8v*>(
                BT + (size_t)(bn + n * 16 + fr) * K + k0 + fg * 8);
            acc4[n] = __builtin_amdgcn_mfma_f32_16x16x32_bf16(af, bf, acc4[n], 0, 0, 0);
        }
    }

    // C/D layout: col = lane&15, row = 4*(lane>>4)+reg  [HW-verified]
    if constexpr (!FUSE3) {
        #pragma unroll
        for (int n = 0; n < 2; ++n) {
            int col = bn + n * 16 + fr;
            #pragma unroll
            for (int r = 0; r < 4; ++r) {
                int orow = r0 + fg * 4 + r;
                float v = fmaxf(acc4[n][r] + bias[col], 0.0f);
                outB[(size_t)orow * 256 + col] = f2bf(v);
            }
        }
    } else {
        // h2 -> LDS only (overwrite the dead agg half of As)
        __syncthreads();   // all waves done reading As in phase B
        #pragma unroll
        for (int n = 0; n < 2; ++n) {
            int col = bn + n * 16 + fr;
            #pragma unroll
            for (int r = 0; r < 4; ++r) {
                int srow = fg * 4 + r;
                float v = fmaxf(acc4[n][r] + bias[col], 0.0f);
                As[srow][col] = f2bf(v);
            }
        }
        __syncthreads();

        // ---- Phase C: [P|Q] = h2 @ [w3|rw3], waves 0-4, 16 cols each ------
        if (wid < 5) {
            f32x4 a3 = {};
            for (int k0 = 0; k0 < 256; k0 += 32) {
                short8v af = *reinterpret_cast<const short8v*>(&As[fr][k0 + fg * 8]);
                short8v bf = *reinterpret_cast<const short8v*>(
                    w3T + (size_t)(wid * 16 + fr) * 256 + k0 + fg * 8);
                a3 = __builtin_amdgcn_mfma_f32_16x16x32_bf16(af, bf, a3, 0, 0, 0);
            }
            int col = wid * 16 + fr;           // 0..79
            #pragma unroll
            for (int r = 0; r < 4; ++r) {
                int orow = r0 + fg * 4 + r;
                float v = a3[r];
                if (col < 40) Pb[(size_t)orow * 40 + col] = f2bf(v);
                else          outQ[(size_t)orow * 40 + (col - 40)] = v + b3[col - 40];
            }
        }
    }
}

// ---------------------------------------------------------------------------
// Fused rezero (gated no-op when alpha==0): agg(x)@rzwT, h0 = x + a*acc.
// ---------------------------------------------------------------------------
__global__ __launch_bounds__(256) void rz_fused(
    const unsigned short* __restrict__ xb, const float* __restrict__ x,
    const int* __restrict__ ell, const int* __restrict__ cnt,
    const unsigned short* __restrict__ rzwT,
    const float* __restrict__ alpha,
    unsigned short* __restrict__ h0b)
{
    float av = alpha[0];
    if (av == 0.0f) return;
    __shared__ unsigned short As[32][136];
    const int r0 = blockIdx.x * 32;
    {
        const int sub = threadIdx.x >> 3;
        const int ln  = threadIdx.x & 7;
        const int row = r0 + sub;
        if (row < N_NODES) {
            int len = cnt[row]; if (len > KMAX) len = KMAX; if (len < 1) len = 1;
            const int* el = ell + (size_t)row * KMAX;
            float acc[16] = {};
            #pragma unroll 2
            for (int e = 0; e < len; ++e) {
                int j = el[e];
                int d = cnt[j]; if (d > KMAX) d = KMAX; if (d < 1) d = 1;
                float w = rsqrtf((float)d);
                const uint4* srcp = reinterpret_cast<const uint4*>(xb + (size_t)j * 128 + ln * 16);
                #pragma unroll
                for (int c4 = 0; c4 < 2; ++c4) {
                    uint4 u = srcp[c4];
                    acc[c4*8+0] += w * bflo(u.x); acc[c4*8+1] += w * bfhi(u.x);
                    acc[c4*8+2] += w * bflo(u.y); acc[c4*8+3] += w * bfhi(u.y);
                    acc[c4*8+4] += w * bflo(u.z); acc[c4*8+5] += w * bfhi(u.z);
                    acc[c4*8+6] += w * bflo(u.w); acc[c4*8+7] += w * bfhi(u.w);
                }
            }
            float s = rsqrtf((float)len);
            #pragma unroll
            for (int c4 = 0; c4 < 2; ++c4) {
                uint4 pk;
                pk.x = (unsigned int)f2bf(acc[c4*8+0]*s) | ((unsigned int)f2bf(acc[c4*8+1]*s) << 16);
                pk.y = (unsigned int)f2bf(acc[c4*8+2]*s) | ((unsigned int)f2bf(acc[c4*8+3]*s) << 16);
                pk.z = (unsigned int)f2bf(acc[c4*8+4]*s) | ((unsigned int)f2bf(acc[c4*8+5]*s) << 16);
                pk.w = (unsigned int)f2bf(acc[c4*8+6]*s) | ((unsigned int)f2bf(acc[c4*8+7]*s) << 16);
                *reinterpret_cast<uint4*>(&As[sub][ln * 16 + c4 * 8]) = pk;
            }
        } else {
            uint4 z = make_uint4(0u, 0u, 0u, 0u);
            *reinterpret_cast<uint4*>(&As[sub][ln * 16]) = z;
            *reinterpret_cast<uint4*>(&As[sub][ln * 16 + 8]) = z;
        }
    }
    __syncthreads();

    const int lane = threadIdx.x & 63;
    const int wid  = threadIdx.x >> 6;
    const int wr   = wid >> 1, wc = wid & 1;
    const int fr   = lane & 15, fg = lane >> 4;

    f32x4 acc[4] = {};
    for (int k0 = 0; k0 < 128; k0 += 32) {
        short8v af = *reinterpret_cast<const short8v*>(&As[wr * 16 + fr][k0 + fg * 8]);
        #pragma unroll
        for (int n = 0; n < 4; ++n) {
            short8v bf = *reinterpret_cast<const short8v*>(
                rzwT + (size_t)(wc * 64 + n * 16 + fr) * 128 + k0 + fg * 8);
            acc[n] = __builtin_amdgcn_mfma_f32_16x16x32_bf16(af, bf, acc[n], 0, 0, 0);
        }
    }
    #pragma unroll
    for (int n = 0; n < 4; ++n) {
        int col = wc * 64 + n * 16 + fr;
        #pragma unroll
        for (int r = 0; r < 4; ++r) {
            int row = r0 + wr * 16 + fg * 4 + r;
            if (row < N_NODES) {
                float v = x[(size_t)row * 128 + col] + av * acc[n][r];
                h0b[(size_t)row * 128 + col] = f2bf(v);
            }
        }
    }
}

// ---------------------------------------------------------------------------
// Final L3 aggregation with LDS-staged edges:
// out[row,0:40] += deg^-1.5 * sum_j dis_j * Pb[j,:]
// ---------------------------------------------------------------------------
__global__ __launch_bounds__(256) void agg_add40(
    const unsigned short* __restrict__ Pb,
    const int* __restrict__ ell, const int* __restrict__ cnt,
    float* __restrict__ out)
{
    __shared__ int   sj[8][KMAX];
    __shared__ float sw[8][KMAX];
    const int sub = threadIdx.x >> 5;
    const int ln  = threadIdx.x & 31;
    const int row = blockIdx.x * 8 + sub;

    int len = 1;
    if (row < N_NODES) {
        len = cnt[row]; if (len > KMAX) len = KMAX; if (len < 1) len = 1;
        const int* el = ell + (size_t)row * KMAX;
        for (int e = ln; e < len; e += 32) {
            int j = el[e];
            int d = cnt[j]; if (d > KMAX) d = KMAX; if (d < 1) d = 1;
            sj[sub][e] = j;
            sw[sub][e] = rsqrtf((float)d);
        }
    }
    __syncthreads();
    if (row >= N_NODES || ln >= 10) return;

    float a0 = 0.0f, a1 = 0.0f, a2 = 0.0f, a3 = 0.0f;
    #pragma unroll 4
    for (int e = 0; e < len; ++e) {
        int   j = sj[sub][e];
        float w = sw[sub][e];
        uint2 u = *reinterpret_cast<const uint2*>(Pb + (size_t)j * 40 + 4 * ln);
        a0 += w * bflo(u.x);
        a1 += w * bfhi(u.x);
        a2 += w * bflo(u.y);
        a3 += w * bfhi(u.y);
    }
    float fd = (float)len;
    float s = rsqrtf(fd) / fd;
    float4* op = reinterpret_cast<float4*>(out + (size_t)row * 40 + 4 * ln);
    float4 v = *op;
    v.x += a0 * s; v.y += a1 * s; v.z += a2 * s; v.w += a3 * s;
    *op = v;
}

extern "C" void kernel_launch(void* const* d_in, const int* in_sizes, int n_in,
                              void* d_out, int out_size, void* d_ws, size_t ws_size,
                              hipStream_t stream)
{
    (void)in_sizes; (void)n_in; (void)out_size; (void)ws_size;
    const float* x     = (const float*)d_in[0];
    const float* adj   = (const float*)d_in[1];
    const float* alpha = (const float*)d_in[2];
    const float* b1    = (const float*)d_in[6];
    const float* b2    = (const float*)d_in[9];
    const float* b3    = (const float*)d_in[12];
    float* out = (float*)d_out;

    char* ws = (char*)d_ws;
    size_t off = 0;
    auto alloc = [&](size_t bytes) -> char* {
        char* q = ws + off;
        off = (off + bytes + 255) & ~(size_t)255;
        return q;
    };
    int*            cnt  = (int*)  alloc((size_t)N_NODES * 4);
    int*            ell  = (int*)  alloc((size_t)N_NODES * KMAX * 4);
    unsigned short* xb   = (unsigned short*)alloc((size_t)N_NODES * 128 * 2);
    unsigned short* h0b  = (unsigned short*)alloc((size_t)N_NODES * 128 * 2);
    unsigned short* h1b  = (unsigned short*)alloc((size_t)N_NODES * 256 * 2);
    unsigned short* Pb   = (unsigned short*)alloc((size_t)N_NODES * 40 * 2);
    unsigned short* rzwT = (unsigned short*)alloc((size_t)128 * 128 * 2);
    unsigned short* w1T  = (unsigned short*)alloc((size_t)256 * 256 * 2);
    unsigned short* w2T  = (unsigned short*)alloc((size_t)256 * 512 * 2);
    unsigned short* w3T  = (unsigned short*)alloc((size_t)128 * 256 * 2);

    Prm p;
    p.x = x; p.rzw = (const float*)d_in[3];
    p.w1 = (const float*)d_in[4]; p.rw1 = (const float*)d_in[5];
    p.w2 = (const float*)d_in[7]; p.rw2 = (const float*)d_in[8];
    p.w3 = (const float*)d_in[10]; p.rw3 = (const float*)d_in[11];
    p.xb = xb; p.rzwT = rzwT; p.w1T = w1T; p.w2T = w2T; p.w3T = w3T;

    zero_cnt<<<(N_NODES + 255) / 256, 256, 0, stream>>>(cnt);
    prep_scan<<<N_NODES / 2, 256, 0, stream>>>(p, adj, ell, cnt);
    rz_fused<<<(N_NODES + 31) / 32, 256, 0, stream>>>(xb, x, ell, cnt, rzwT, alpha, h0b);
    layer_fused<128, false><<<N_NODES / 16, 512, 0, stream>>>(
        xb, h0b, alpha, ell, cnt, w1T, b1, h1b, nullptr, nullptr, nullptr, nullptr);
    layer_fused<256, true><<<N_NODES / 16, 512, 0, stream>>>(
        h1b, h1b, nullptr, ell, cnt, w2T, b2, nullptr, w3T, b3, Pb, out);
    agg_add40<<<(N_NODES + 7) / 8, 256, 0, stream>>>(Pb, ell, cnt, out);
}